// Round 1
// baseline (1965.362 us; speedup 1.0000x reference)
//
#include <hip/hip_runtime.h>
#include <hip/hip_bf16.h>

#define HID 128
#define EDIM 16

// ---------------- GEMM: C[N,128] = (A (+A2)) @ W[K,128] + bias ----------------
// block 256 threads: ch = tid&63 (cols ch, ch+64), rg = tid>>6 (8 rows each) -> 32 rows/block
template<int K>
__global__ void gemm_kernel(const float* __restrict__ A, const float* __restrict__ A2,
                            const float* __restrict__ W, const float* __restrict__ bias,
                            float* __restrict__ C, int Nrows)
{
    __shared__ __align__(16) float Alds[32 * K];
    int tid = threadIdx.x;
    int rbase = blockIdx.x * 32;
    for (int idx = tid; idx < 32 * K; idx += 256) {
        int r = idx / K, k = idx - r * K;
        int gr = rbase + r;
        float v = 0.f;
        if (gr < Nrows) {
            v = A[(long)gr * K + k];
            if (A2) v += A2[(long)gr * K + k];
        }
        Alds[r * K + k] = v;
    }
    __syncthreads();
    int ch = tid & 63;
    int r0 = (tid >> 6) * 8;
    float acc0[8], acc1[8];
    float b0 = bias[ch], b1 = bias[ch + 64];
#pragma unroll
    for (int r = 0; r < 8; ++r) { acc0[r] = b0; acc1[r] = b1; }
    for (int k = 0; k < K; k += 4) {
        float w0[4], w1[4];
#pragma unroll
        for (int kk = 0; kk < 4; ++kk) {
            w0[kk] = W[(k + kk) * HID + ch];
            w1[kk] = W[(k + kk) * HID + ch + 64];
        }
#pragma unroll
        for (int r = 0; r < 8; ++r) {
            const float4 a4 = *(const float4*)&Alds[(r0 + r) * K + k];
            acc0[r] += a4.x * w0[0] + a4.y * w0[1] + a4.z * w0[2] + a4.w * w0[3];
            acc1[r] += a4.x * w1[0] + a4.y * w1[1] + a4.z * w1[2] + a4.w * w1[3];
        }
    }
#pragma unroll
    for (int r = 0; r < 8; ++r) {
        int gr = rbase + r0 + r;
        if (gr < Nrows) {
            C[(long)gr * HID + ch] = acc0[r];
            C[(long)gr * HID + ch + 64] = acc1[r];
        }
    }
}

// -------- Edge message: agg[dst] += relu(h[src] + edge_attr@We + be) --------
// block 256 = 2 edges x 128 channels; 32 edges per block
__global__ void edge_kernel(const float* __restrict__ h, const float* __restrict__ ea,
                            const int* __restrict__ src, const int* __restrict__ dst,
                            const float* __restrict__ We, const float* __restrict__ be,
                            float* __restrict__ agg, int E)
{
    __shared__ float Wl[EDIM * HID];
    __shared__ float bl[HID];
    int tid = threadIdx.x;
    for (int i = tid; i < EDIM * HID; i += 256) Wl[i] = We[i];
    if (tid < HID) bl[tid] = be[tid];
    __syncthreads();
    int j = tid & 127, sub = tid >> 7;
    int base = blockIdx.x * 32;
    for (int it = 0; it < 16; ++it) {
        int e = base + it * 2 + sub;
        if (e >= E) break;
        const float4* eap = (const float4*)(ea + (long)e * EDIM);
        float4 e0 = eap[0], e1 = eap[1], e2 = eap[2], e3 = eap[3];
        float acc = bl[j];
        acc += e0.x * Wl[0 * 128 + j] + e0.y * Wl[1 * 128 + j] + e0.z * Wl[2 * 128 + j] + e0.w * Wl[3 * 128 + j];
        acc += e1.x * Wl[4 * 128 + j] + e1.y * Wl[5 * 128 + j] + e1.z * Wl[6 * 128 + j] + e1.w * Wl[7 * 128 + j];
        acc += e2.x * Wl[8 * 128 + j] + e2.y * Wl[9 * 128 + j] + e2.z * Wl[10 * 128 + j] + e2.w * Wl[11 * 128 + j];
        acc += e3.x * Wl[12 * 128 + j] + e3.y * Wl[13 * 128 + j] + e3.z * Wl[14 * 128 + j] + e3.w * Wl[15 * 128 + j];
        int s = src[e], d = dst[e];
        float m = h[(long)s * HID + j] + acc;
        m = fmaxf(m, 0.f);
        atomicAdd(&agg[(long)d * HID + j], m);
    }
}

// ---------------- BatchNorm stats: stats[0:128]=sum, [128:256]=sumsq ----------------
__global__ void bn_stats(const float* __restrict__ X, float* __restrict__ stats, int Nrows)
{
    __shared__ float s0[256], s1[256];
    int tid = threadIdx.x;
    int ch = tid & 127, half = tid >> 7;
    float sum = 0.f, sq = 0.f;
    for (int r = blockIdx.x * 2 + half; r < Nrows; r += gridDim.x * 2) {
        float v = X[(long)r * HID + ch];
        sum += v; sq += v * v;
    }
    s0[tid] = sum; s1[tid] = sq;
    __syncthreads();
    if (tid < 128) {
        atomicAdd(&stats[ch], s0[tid] + s0[tid + 128]);
        atomicAdd(&stats[128 + ch], s1[tid] + s1[tid + 128]);
    }
}

// ---------------- BN apply + ReLU (out may alias X) ----------------
__global__ void bn_apply(const float* __restrict__ X, float* __restrict__ out,
                         const float* __restrict__ stats, const float* __restrict__ g,
                         const float* __restrict__ b, long total, float invN)
{
    long idx = (long)blockIdx.x * blockDim.x + threadIdx.x;
    if (idx >= total) return;
    int ch = (int)(idx & 127);
    float mean = stats[ch] * invN;
    float var = stats[128 + ch] * invN - mean * mean;
    float rstd = rsqrtf(var + 1e-5f);
    float v = (X[idx] - mean) * rstd * g[ch] + b[ch];
    out[idx] = fmaxf(v, 0.f);
}

// ---------------- segment boundaries via binary search (batch sorted) ----------------
__global__ void starts_kernel(const int* __restrict__ batch, int* __restrict__ starts,
                              int Nn, int Gn)
{
    int g = blockIdx.x * blockDim.x + threadIdx.x;
    if (g > Gn) return;
    int lo = 0, hi = Nn;
    while (lo < hi) { int mid = (lo + hi) >> 1; if (batch[mid] < g) lo = mid + 1; else hi = mid; }
    starts[g] = lo;
}

// ---------------- per-layer pooling into z slices: mean->z[:, l*128], max->z[:, 384+l*128] ----------------
__global__ void pool_kernel(const float* __restrict__ h, const int* __restrict__ starts,
                            float* __restrict__ z, int l)
{
    int g = blockIdx.x, j = threadIdx.x;
    int s = starts[g], e = starts[g + 1];
    float sum = 0.f, mx = 0.f;  // h >= 0 after ReLU
    for (int n = s; n < e; ++n) {
        float v = h[(long)n * HID + j];
        sum += v; mx = fmaxf(mx, v);
    }
    float cnt = (float)(e - s);
    z[(long)g * 768 + l * 128 + j] = sum / fmaxf(cnt, 1.f);
    z[(long)g * 768 + 384 + l * 128 + j] = mx;
}

// ---------------- head GEMM: zr[G,128] = z[G,768] @ W[768,128] + b ----------------
__global__ void head_gemm1(const float* __restrict__ z, const float* __restrict__ W,
                           const float* __restrict__ bias, float* __restrict__ zr)
{
    __shared__ __align__(16) float zl[768];
    int g = blockIdx.x, j = threadIdx.x;
    for (int i = j; i < 768; i += 128) zl[i] = z[(long)g * 768 + i];
    __syncthreads();
    float acc = bias[j];
    for (int k = 0; k < 768; k += 4) {
        float4 a4 = *(const float4*)&zl[k];
        acc += a4.x * W[k * 128 + j] + a4.y * W[(k + 1) * 128 + j]
             + a4.z * W[(k + 2) * 128 + j] + a4.w * W[(k + 3) * 128 + j];
    }
    zr[(long)g * 128 + j] = acc;
}

// ---------------- head BN stats (single block) ----------------
__global__ void head_stats(const float* __restrict__ zr, float* __restrict__ ms, int Gn)
{
    int j = threadIdx.x;  // 128 threads
    float sum = 0.f, sq = 0.f;
    for (int r = 0; r < Gn; ++r) { float v = zr[(long)r * 128 + j]; sum += v; sq += v * v; }
    float mean = sum / (float)Gn;
    float var = sq / (float)Gn - mean * mean;
    ms[j] = mean;
    ms[128 + j] = rsqrtf(var + 1e-5f);
}

// ---------------- head final: out[g] = relu(bn(zr)) @ W2 + b2 ----------------
__global__ void head_final(const float* __restrict__ zr, const float* __restrict__ ms,
                           const float* __restrict__ hg, const float* __restrict__ hb,
                           const float* __restrict__ W2, const float* __restrict__ b2,
                           float* __restrict__ out)
{
    int g = blockIdx.x, j = threadIdx.x;
    float v = zr[(long)g * 128 + j];
    v = (v - ms[j]) * ms[128 + j] * hg[j] + hb[j];
    v = fmaxf(v, 0.f);
    float p = v * W2[j];
#pragma unroll
    for (int off = 32; off > 0; off >>= 1) p += __shfl_down(p, off, 64);
    __shared__ float partial[2];
    if ((j & 63) == 0) partial[j >> 6] = p;
    __syncthreads();
    if (j == 0) out[g] = partial[0] + partial[1] + b2[0];
}

extern "C" void kernel_launch(void* const* d_in, const int* in_sizes, int n_in,
                              void* d_out, int out_size, void* d_ws, size_t ws_size,
                              hipStream_t stream)
{
    const float* x         = (const float*)d_in[0];
    const float* edge_attr = (const float*)d_in[1];
    const int*   src       = (const int*)d_in[2];
    const int*   dst       = (const int*)d_in[3];
    const int*   batch     = (const int*)d_in[4];
    const float* Wp        = (const float*)d_in[5];
    const float* bp        = (const float*)d_in[6];
    const float* conv_We   = (const float*)d_in[7];
    const float* conv_be   = (const float*)d_in[8];
    const float* conv_W1   = (const float*)d_in[9];
    const float* conv_b1   = (const float*)d_in[10];
    const float* conv_g1   = (const float*)d_in[11];
    const float* conv_bt1  = (const float*)d_in[12];
    const float* conv_W2   = (const float*)d_in[13];
    const float* conv_b2   = (const float*)d_in[14];
    const float* bn_g      = (const float*)d_in[15];
    const float* bn_b      = (const float*)d_in[16];
    const float* head_W1   = (const float*)d_in[17];
    const float* head_b1   = (const float*)d_in[18];
    const float* head_g    = (const float*)d_in[19];
    const float* head_bt   = (const float*)d_in[20];
    const float* head_W2   = (const float*)d_in[21];
    const float* head_b2   = (const float*)d_in[22];

    const int N = in_sizes[4];            // 50000
    const int E = in_sizes[2];            // 800000
    const int G = out_size;               // 256
    const int IN_CH = in_sizes[0] / N;    // 64
    const int L = 3;

    float* h     = (float*)d_ws;                    // N*128
    float* agg   = h + (long)N * HID;               // N*128
    float* z     = agg + (long)N * HID;             // G*768
    float* zr    = z + (long)G * 768;               // G*128
    float* stats = zr + (long)G * HID;              // 256
    float* ms    = stats + 256;                     // 256
    int*   starts= (int*)(ms + 256);                // G+1

    (void)n_in; (void)ws_size; (void)IN_CH;

    const long totalNH = (long)N * HID;
    const float invN = 1.0f / (float)N;
    const int gemmBlocks = (N + 31) / 32;
    const int bnApplyBlocks = (int)((totalNH + 255) / 256);

    // segment boundaries (independent of layer loop)
    starts_kernel<<<1, 512, 0, stream>>>(batch, starts, N, G);

    // h = x @ Wp + bp
    gemm_kernel<64><<<gemmBlocks, 256, 0, stream>>>(x, nullptr, Wp, bp, h, N);

    for (int l = 0; l < L; ++l) {
        hipMemsetAsync(agg, 0, totalNH * sizeof(float), stream);
        edge_kernel<<<(E + 31) / 32, 256, 0, stream>>>(
            h, edge_attr, src, dst, conv_We + (long)l * EDIM * HID, conv_be + l * HID, agg, E);
        // t = (h + agg) @ W1 + b1   (in-place into agg: block stages its rows before writing)
        gemm_kernel<128><<<gemmBlocks, 256, 0, stream>>>(
            h, agg, conv_W1 + (long)l * HID * HID, conv_b1 + l * HID, agg, N);
        hipMemsetAsync(stats, 0, 256 * sizeof(float), stream);
        bn_stats<<<512, 256, 0, stream>>>(agg, stats, N);
        bn_apply<<<bnApplyBlocks, 256, 0, stream>>>(
            agg, agg, stats, conv_g1 + l * HID, conv_bt1 + l * HID, totalNH, invN);
        // t = t @ W2 + b2 (in-place)
        gemm_kernel<128><<<gemmBlocks, 256, 0, stream>>>(
            agg, nullptr, conv_W2 + (long)l * HID * HID, conv_b2 + l * HID, agg, N);
        hipMemsetAsync(stats, 0, 256 * sizeof(float), stream);
        bn_stats<<<512, 256, 0, stream>>>(agg, stats, N);
        bn_apply<<<bnApplyBlocks, 256, 0, stream>>>(
            agg, h, stats, bn_g + l * HID, bn_b + l * HID, totalNH, invN);
        // pool this layer's h into z slices (JK-cat decomposes per layer)
        pool_kernel<<<G, 128, 0, stream>>>(h, starts, z, l);
    }

    head_gemm1<<<G, 128, 0, stream>>>(z, head_W1, head_b1, zr);
    head_stats<<<1, 128, 0, stream>>>(zr, ms, G);
    head_final<<<G, 128, 0, stream>>>(zr, ms, head_g, head_bt, head_W2, head_b2, (float*)d_out);
}

// Round 2
// 1665.244 us; speedup vs baseline: 1.1802x; 1.1802x over previous
//
#include <hip/hip_runtime.h>
#include <hip/hip_bf16.h>

#define HID 128
#define EDIM 16

// ================= CSR build (once per call; reused for all 3 layers) =================
__global__ void hist_kernel(const int* __restrict__ dst, int* __restrict__ deg, int E)
{
    int e = blockIdx.x * 256 + threadIdx.x;
    if (e < E) atomicAdd(&deg[dst[e]], 1);
}

// deg and cursor may alias (deg is consumed, cursor produced at same index)
__global__ void scan_kernel(const int* deg, int* row_start, int* cursor, int Nn)
{
    __shared__ int sh[1024];
    __shared__ int carry;
    int tid = threadIdx.x;
    if (tid == 0) carry = 0;
    __syncthreads();
    for (int base = 0; base < Nn; base += 1024) {
        int i = base + tid;
        int v = (i < Nn) ? deg[i] : 0;
        sh[tid] = v;
        __syncthreads();
        for (int off = 1; off < 1024; off <<= 1) {
            int tv = (tid >= off) ? sh[tid - off] : 0;
            __syncthreads();
            sh[tid] += tv;
            __syncthreads();
        }
        int incl = sh[tid];
        int c0 = carry;
        if (i < Nn) { int rs = c0 + incl - v; row_start[i] = rs; cursor[i] = rs; }
        __syncthreads();
        if (tid == 1023) carry = c0 + incl;
        __syncthreads();
    }
    if (tid == 0) row_start[Nn] = carry;
}

__global__ void scatter_kernel(const int* __restrict__ src, const int* __restrict__ dst,
                               int* cursor, int* __restrict__ perm,
                               int* __restrict__ src_perm, int E)
{
    int e = blockIdx.x * 256 + threadIdx.x;
    if (e >= E) return;
    int pos = atomicAdd(&cursor[dst[e]], 1);
    perm[pos] = e;
    src_perm[pos] = src[e];
}

// ====== Node-centric aggregation: t[n] = h[n] + sum_{e in in(n)} relu(h[src]+ea@We+be) ======
// block 256 = 2 nodes x 128 channels; no atomics, one coalesced store per node row
__global__ void aggregate_kernel(const float* __restrict__ h, const float* __restrict__ ea,
                                 const int* __restrict__ src_perm, const int* __restrict__ perm,
                                 const int* __restrict__ row_start,
                                 const float* __restrict__ We, const float* __restrict__ be,
                                 float* __restrict__ t, int Nn)
{
    __shared__ float Wl[EDIM * HID];
    __shared__ float bl[HID];
    int tid = threadIdx.x;
    for (int i = tid; i < EDIM * HID; i += 256) Wl[i] = We[i];
    if (tid < HID) bl[tid] = be[tid];
    __syncthreads();
    int node = blockIdx.x * 2 + (tid >> 7);
    int j = tid & 127;
    if (node >= Nn) return;
    float acc = h[(long)node * HID + j];
    int p0 = row_start[node], p1 = row_start[node + 1];
    float bj = bl[j];
    for (int p = p0; p < p1; ++p) {
        int e = perm[p];
        int s = src_perm[p];
        const float4* eap = (const float4*)(ea + (long)e * EDIM);
        float4 e0 = eap[0], e1 = eap[1], e2 = eap[2], e3 = eap[3];
        float m = bj;
        m += e0.x * Wl[0 * 128 + j] + e0.y * Wl[1 * 128 + j] + e0.z * Wl[2 * 128 + j] + e0.w * Wl[3 * 128 + j];
        m += e1.x * Wl[4 * 128 + j] + e1.y * Wl[5 * 128 + j] + e1.z * Wl[6 * 128 + j] + e1.w * Wl[7 * 128 + j];
        m += e2.x * Wl[8 * 128 + j] + e2.y * Wl[9 * 128 + j] + e2.z * Wl[10 * 128 + j] + e2.w * Wl[11 * 128 + j];
        m += e3.x * Wl[12 * 128 + j] + e3.y * Wl[13 * 128 + j] + e3.z * Wl[14 * 128 + j] + e3.w * Wl[15 * 128 + j];
        m += h[(long)s * HID + j];
        acc += fmaxf(m, 0.f);
    }
    t[(long)node * HID + j] = acc;
}

// ================= GEMM with optional fused pre-BN(+ReLU) and fused post-BN stats =================
// C[N,128] = f(A) @ W[K,128] + bias ; f = identity or relu(BN(.)) using preStats
// POST_STATS: per-column sum/sumsq of C accumulated into postStats via 1 atomic/col/block
template<int K, bool PRE_BN, bool POST_STATS>
__global__ void gemm_kernel(const float* __restrict__ A, const float* __restrict__ W,
                            const float* __restrict__ bias,
                            const float* __restrict__ preStats, const float* __restrict__ preG,
                            const float* __restrict__ preB,
                            float* __restrict__ C, float* __restrict__ postStats,
                            int Nrows, float invN)
{
    __shared__ __align__(16) float Alds[32 * K];
    __shared__ float sc[PRE_BN ? K : 1], sb[PRE_BN ? K : 1];
    int tid = threadIdx.x;
    int rbase = blockIdx.x * 32;
    if (PRE_BN) {
        if (tid < K) {
            float mean = preStats[tid] * invN;
            float var = preStats[K + tid] * invN - mean * mean;
            float rstd = rsqrtf(var + 1e-5f);
            float g = preG[tid];
            sc[tid] = rstd * g;
            sb[tid] = preB[tid] - mean * rstd * g;
        }
        __syncthreads();
    }
    for (int idx = tid; idx < 32 * K; idx += 256) {
        int r = idx / K, k = idx - r * K;
        int gr = rbase + r;
        float v = 0.f;
        if (gr < Nrows) {
            v = A[(long)gr * K + k];
            if (PRE_BN) v = fmaxf(v * sc[k] + sb[k], 0.f);
        }
        Alds[r * K + k] = v;
    }
    __syncthreads();
    int ch = tid & 63;
    int r0 = (tid >> 6) * 8;
    float acc0[8], acc1[8];
    float b0 = bias[ch], b1 = bias[ch + 64];
#pragma unroll
    for (int r = 0; r < 8; ++r) { acc0[r] = b0; acc1[r] = b1; }
    for (int k = 0; k < K; k += 4) {
        float w0[4], w1[4];
#pragma unroll
        for (int kk = 0; kk < 4; ++kk) {
            w0[kk] = W[(k + kk) * HID + ch];
            w1[kk] = W[(k + kk) * HID + ch + 64];
        }
#pragma unroll
        for (int r = 0; r < 8; ++r) {
            const float4 a4 = *(const float4*)&Alds[(r0 + r) * K + k];
            acc0[r] += a4.x * w0[0] + a4.y * w0[1] + a4.z * w0[2] + a4.w * w0[3];
            acc1[r] += a4.x * w1[0] + a4.y * w1[1] + a4.z * w1[2] + a4.w * w1[3];
        }
    }
#pragma unroll
    for (int r = 0; r < 8; ++r) {
        int gr = rbase + r0 + r;
        if (gr < Nrows) {
            C[(long)gr * HID + ch] = acc0[r];
            C[(long)gr * HID + ch + 64] = acc1[r];
        }
    }
    if (POST_STATS) {
        __shared__ float redS[4 * 128], redQ[4 * 128];
        int rg = tid >> 6;
        float sA = 0.f, qA = 0.f, sB = 0.f, qB = 0.f;
#pragma unroll
        for (int r = 0; r < 8; ++r) {
            int gr = rbase + r0 + r;
            if (gr < Nrows) {
                sA += acc0[r]; qA += acc0[r] * acc0[r];
                sB += acc1[r]; qB += acc1[r] * acc1[r];
            }
        }
        redS[rg * 128 + ch] = sA; redS[rg * 128 + ch + 64] = sB;
        redQ[rg * 128 + ch] = qA; redQ[rg * 128 + ch + 64] = qB;
        __syncthreads();
        if (tid < 128) {
            float S = redS[tid] + redS[128 + tid] + redS[256 + tid] + redS[384 + tid];
            float Q = redQ[tid] + redQ[128 + tid] + redQ[256 + tid] + redQ[384 + tid];
            atomicAdd(&postStats[tid], S);
            atomicAdd(&postStats[128 + tid], Q);
        }
    }
}

// ================= BN apply + ReLU (out may alias X) =================
__global__ void bn_apply(const float* __restrict__ X, float* __restrict__ out,
                         const float* __restrict__ stats, const float* __restrict__ g,
                         const float* __restrict__ b, long total, float invN)
{
    long idx = (long)blockIdx.x * blockDim.x + threadIdx.x;
    if (idx >= total) return;
    int ch = (int)(idx & 127);
    float mean = stats[ch] * invN;
    float var = stats[128 + ch] * invN - mean * mean;
    float rstd = rsqrtf(var + 1e-5f);
    float v = (X[idx] - mean) * rstd * g[ch] + b[ch];
    out[idx] = fmaxf(v, 0.f);
}

// ================= segment boundaries (batch sorted) =================
__global__ void starts_kernel(const int* __restrict__ batch, int* __restrict__ starts,
                              int Nn, int Gn)
{
    int g = blockIdx.x * blockDim.x + threadIdx.x;
    if (g > Gn) return;
    int lo = 0, hi = Nn;
    while (lo < hi) { int mid = (lo + hi) >> 1; if (batch[mid] < g) lo = mid + 1; else hi = mid; }
    starts[g] = lo;
}

// ============ per-layer pooling into z slices: mean->z[:, l*128], max->z[:, 384+l*128] ============
__global__ void pool_kernel(const float* __restrict__ h, const int* __restrict__ starts,
                            float* __restrict__ z, int l)
{
    int g = blockIdx.x;
    int tid = threadIdx.x;
    int j = tid & 127, half = tid >> 7;
    int s = starts[g], e = starts[g + 1];
    float sum = 0.f, mx = 0.f;  // h >= 0 after ReLU
    for (int n = s + half; n < e; n += 2) {
        float v = h[(long)n * HID + j];
        sum += v; mx = fmaxf(mx, v);
    }
    __shared__ float ls[256], lm[256];
    ls[tid] = sum; lm[tid] = mx;
    __syncthreads();
    if (tid < 128) {
        sum = ls[tid] + ls[tid + 128];
        mx = fmaxf(lm[tid], lm[tid + 128]);
        float cnt = (float)(e - s);
        z[(long)g * 768 + l * 128 + tid] = sum / fmaxf(cnt, 1.f);
        z[(long)g * 768 + 384 + l * 128 + tid] = mx;
    }
}

// ================= head =================
__global__ void head_gemm1(const float* __restrict__ z, const float* __restrict__ W,
                           const float* __restrict__ bias, float* __restrict__ zr)
{
    __shared__ __align__(16) float zl[768];
    int g = blockIdx.x, j = threadIdx.x;
    for (int i = j; i < 768; i += 128) zl[i] = z[(long)g * 768 + i];
    __syncthreads();
    float acc = bias[j];
    for (int k = 0; k < 768; k += 4) {
        float4 a4 = *(const float4*)&zl[k];
        acc += a4.x * W[k * 128 + j] + a4.y * W[(k + 1) * 128 + j]
             + a4.z * W[(k + 2) * 128 + j] + a4.w * W[(k + 3) * 128 + j];
    }
    zr[(long)g * 128 + j] = acc;
}

__global__ void head_stats(const float* __restrict__ zr, float* __restrict__ ms, int Gn)
{
    int j = threadIdx.x;  // 128 threads
    float sum = 0.f, sq = 0.f;
    for (int r = 0; r < Gn; ++r) { float v = zr[(long)r * 128 + j]; sum += v; sq += v * v; }
    float mean = sum / (float)Gn;
    float var = sq / (float)Gn - mean * mean;
    ms[j] = mean;
    ms[128 + j] = rsqrtf(var + 1e-5f);
}

__global__ void head_final(const float* __restrict__ zr, const float* __restrict__ ms,
                           const float* __restrict__ hg, const float* __restrict__ hb,
                           const float* __restrict__ W2, const float* __restrict__ b2,
                           float* __restrict__ out)
{
    int g = blockIdx.x, j = threadIdx.x;
    float v = zr[(long)g * 128 + j];
    v = (v - ms[j]) * ms[128 + j] * hg[j] + hb[j];
    v = fmaxf(v, 0.f);
    float p = v * W2[j];
#pragma unroll
    for (int off = 32; off > 0; off >>= 1) p += __shfl_down(p, off, 64);
    __shared__ float partial[2];
    if ((j & 63) == 0) partial[j >> 6] = p;
    __syncthreads();
    if (j == 0) out[g] = partial[0] + partial[1] + b2[0];
}

extern "C" void kernel_launch(void* const* d_in, const int* in_sizes, int n_in,
                              void* d_out, int out_size, void* d_ws, size_t ws_size,
                              hipStream_t stream)
{
    const float* x         = (const float*)d_in[0];
    const float* edge_attr = (const float*)d_in[1];
    const int*   src       = (const int*)d_in[2];
    const int*   dst       = (const int*)d_in[3];
    const int*   batch     = (const int*)d_in[4];
    const float* Wp        = (const float*)d_in[5];
    const float* bp        = (const float*)d_in[6];
    const float* conv_We   = (const float*)d_in[7];
    const float* conv_be   = (const float*)d_in[8];
    const float* conv_W1   = (const float*)d_in[9];
    const float* conv_b1   = (const float*)d_in[10];
    const float* conv_g1   = (const float*)d_in[11];
    const float* conv_bt1  = (const float*)d_in[12];
    const float* conv_W2   = (const float*)d_in[13];
    const float* conv_b2   = (const float*)d_in[14];
    const float* bn_g      = (const float*)d_in[15];
    const float* bn_b      = (const float*)d_in[16];
    const float* head_W1   = (const float*)d_in[17];
    const float* head_b1   = (const float*)d_in[18];
    const float* head_g    = (const float*)d_in[19];
    const float* head_bt   = (const float*)d_in[20];
    const float* head_W2   = (const float*)d_in[21];
    const float* head_b2   = (const float*)d_in[22];

    const int N = in_sizes[4];            // 50000
    const int E = in_sizes[2];            // 800000
    const int G = out_size;               // 256
    const int L = 3;

    float* h        = (float*)d_ws;                  // N*128
    float* t        = h + (long)N * HID;             // N*128
    float* z        = t + (long)N * HID;             // G*768
    float* zr       = z + (long)G * 768;             // G*128
    float* statsAll = zr + (long)G * HID;            // 7*256 (3 layers x {inner,outer} + head ms)
    int*   starts   = (int*)(statsAll + 7 * 256);    // G+1
    int*   row_start= starts + (G + 1);              // N+1
    int*   cursor   = row_start + (N + 1);           // N (doubles as deg)
    int*   perm     = cursor + N;                    // E
    int*   src_perm = perm + E;                      // E
    float* ms       = statsAll + 6 * 256;

    (void)n_in; (void)ws_size;

    const long totalNH = (long)N * HID;
    const float invN = 1.0f / (float)N;
    const int gemmBlocks = (N + 31) / 32;
    const int bnApplyBlocks = (int)((totalNH + 255) / 256);

    // ---- CSR build (edge structure shared by all layers) ----
    hipMemsetAsync(cursor, 0, (size_t)N * sizeof(int), stream);
    hist_kernel<<<(E + 255) / 256, 256, 0, stream>>>(dst, cursor, E);
    scan_kernel<<<1, 1024, 0, stream>>>(cursor, row_start, cursor, N);
    scatter_kernel<<<(E + 255) / 256, 256, 0, stream>>>(src, dst, cursor, perm, src_perm, E);
    starts_kernel<<<1, 512, 0, stream>>>(batch, starts, N, G);
    hipMemsetAsync(statsAll, 0, 7 * 256 * sizeof(float), stream);

    // h = x @ Wp + bp
    gemm_kernel<64, false, false><<<gemmBlocks, 256, 0, stream>>>(
        x, Wp, bp, nullptr, nullptr, nullptr, h, nullptr, N, invN);

    for (int l = 0; l < L; ++l) {
        float* sI = statsAll + l * 512;
        float* sO = sI + 256;
        aggregate_kernel<<<(N + 1) / 2, 256, 0, stream>>>(
            h, edge_attr, src_perm, perm, row_start,
            conv_We + (long)l * EDIM * HID, conv_be + l * HID, t, N);
        // t = t @ W1 + b1, fused inner-BN stats
        gemm_kernel<128, false, true><<<gemmBlocks, 256, 0, stream>>>(
            t, conv_W1 + (long)l * HID * HID, conv_b1 + l * HID,
            nullptr, nullptr, nullptr, t, sI, N, invN);
        // t = relu(BN_inner(t)) @ W2 + b2, fused outer-BN stats
        gemm_kernel<128, true, true><<<gemmBlocks, 256, 0, stream>>>(
            t, conv_W2 + (long)l * HID * HID, conv_b2 + l * HID,
            sI, conv_g1 + l * HID, conv_bt1 + l * HID, t, sO, N, invN);
        // h = relu(BN_outer(t))
        bn_apply<<<bnApplyBlocks, 256, 0, stream>>>(
            t, h, sO, bn_g + l * HID, bn_b + l * HID, totalNH, invN);
        pool_kernel<<<G, 256, 0, stream>>>(h, starts, z, l);
    }

    head_gemm1<<<G, 128, 0, stream>>>(z, head_W1, head_b1, zr);
    head_stats<<<1, 128, 0, stream>>>(zr, ms, G);
    head_final<<<G, 128, 0, stream>>>(zr, ms, head_g, head_bt, head_W2, head_b2, (float*)d_out);
}

// Round 3
// 1351.932 us; speedup vs baseline: 1.4537x; 1.2318x over previous
//
#include <hip/hip_runtime.h>
#include <hip/hip_bf16.h>

#define HID 128
#define EDIM 16

// ================= CSR build =================
__global__ void hist_kernel(const int* __restrict__ dst, int* __restrict__ deg, int E)
{
    int e = blockIdx.x * 256 + threadIdx.x;
    if (e < E) atomicAdd(&deg[dst[e]], 1);
}

__global__ void block_sum_kernel(const int* __restrict__ deg, int* __restrict__ bsum, int Nn)
{
    int i = blockIdx.x * 256 + threadIdx.x;
    int v = (i < Nn) ? deg[i] : 0;
#pragma unroll
    for (int off = 32; off > 0; off >>= 1) v += __shfl_down(v, off, 64);
    __shared__ int ws[4];
    if ((threadIdx.x & 63) == 0) ws[threadIdx.x >> 6] = v;
    __syncthreads();
    if (threadIdx.x == 0) bsum[blockIdx.x] = ws[0] + ws[1] + ws[2] + ws[3];
}

// exclusive scan of bsum (nb <= 256); total -> *total_out
__global__ void bsum_scan_kernel(int* bsum, int nb, int* total_out)
{
    __shared__ int sh[256];
    int tid = threadIdx.x;
    int v = (tid < nb) ? bsum[tid] : 0;
    sh[tid] = v;
    __syncthreads();
    for (int off = 1; off < 256; off <<= 1) {
        int tv = (tid >= off) ? sh[tid - off] : 0;
        __syncthreads();
        sh[tid] += tv;
        __syncthreads();
    }
    if (tid < nb) bsum[tid] = sh[tid] - v;
    if (tid == 255) *total_out = sh[255];
}

__global__ void block_scan_kernel(const int* __restrict__ deg, const int* __restrict__ bsum,
                                  int* __restrict__ row_start, int* __restrict__ cursor, int Nn)
{
    __shared__ int sh[256];
    int tid = threadIdx.x;
    int i = blockIdx.x * 256 + tid;
    int v = (i < Nn) ? deg[i] : 0;
    sh[tid] = v;
    __syncthreads();
    for (int off = 1; off < 256; off <<= 1) {
        int tv = (tid >= off) ? sh[tid - off] : 0;
        __syncthreads();
        sh[tid] += tv;
        __syncthreads();
    }
    if (i < Nn) {
        int excl = sh[tid] - v + bsum[blockIdx.x];
        row_start[i] = excl;
        cursor[i] = excl;
    }
}

__global__ void scatter_kernel(const int* __restrict__ src, const int* __restrict__ dst,
                               int* cursor, int* __restrict__ perm,
                               int* __restrict__ src_perm, int E)
{
    int e = blockIdx.x * 256 + threadIdx.x;
    if (e >= E) return;
    int pos = atomicAdd(&cursor[dst[e]], 1);
    perm[pos] = e;
    src_perm[pos] = src[e];
}

// gather edge_attr into CSR order (coalesced writes; one float4 per thread)
__global__ void gather_ea_kernel(const float* __restrict__ ea, const int* __restrict__ perm,
                                 float* __restrict__ ea_perm, int E)
{
    int idx = blockIdx.x * 256 + threadIdx.x;
    int p = idx >> 2, c = (idx & 3) * 4;
    if (p >= E) return;
    int e = perm[p];
    *(float4*)&ea_perm[(long)p * EDIM + c] = *(const float4*)&ea[(long)e * EDIM + c];
}

// ====== Node-centric aggregation, W in registers (no LDS) ======
__device__ __forceinline__ float matv16(const float4& a0, const float4& a1,
                                        const float4& a2, const float4& a3, const float* w)
{
    return a0.x*w[0]+a0.y*w[1]+a0.z*w[2]+a0.w*w[3]
         + a1.x*w[4]+a1.y*w[5]+a1.z*w[6]+a1.w*w[7]
         + a2.x*w[8]+a2.y*w[9]+a2.z*w[10]+a2.w*w[11]
         + a3.x*w[12]+a3.y*w[13]+a3.z*w[14]+a3.w*w[15];
}

template<bool GATH>
__global__ void aggregate_kernel(const float* __restrict__ h, const float* __restrict__ eaG,
                                 const int* __restrict__ perm,
                                 const int* __restrict__ src_perm, const int* __restrict__ row_start,
                                 const float* __restrict__ We, const float* __restrict__ be,
                                 float* __restrict__ t, int Nn)
{
    int tid = threadIdx.x;
    int j = tid & 127;
    float w[16];
#pragma unroll
    for (int k = 0; k < 16; ++k) w[k] = We[k * HID + j];
    float bj = be[j];
    int node = blockIdx.x * 2 + (tid >> 7);
    if (node >= Nn) return;
    float acc = h[(long)node * HID + j];
    int p0 = row_start[node], p1 = row_start[node + 1];
    int p = p0;
    for (; p + 1 < p1; p += 2) {
        long q0 = GATH ? (long)p : (long)perm[p];
        long q1 = GATH ? (long)(p + 1) : (long)perm[p + 1];
        const float4* ra = (const float4*)(eaG + q0 * EDIM);
        const float4* rb = (const float4*)(eaG + q1 * EDIM);
        int s0 = src_perm[p], s1 = src_perm[p + 1];
        float4 a0 = ra[0], a1 = ra[1], a2 = ra[2], a3 = ra[3];
        float4 b0 = rb[0], b1 = rb[1], b2 = rb[2], b3 = rb[3];
        float h0 = h[(long)s0 * HID + j];
        float h1 = h[(long)s1 * HID + j];
        float m0 = bj + matv16(a0, a1, a2, a3, w) + h0;
        float m1 = bj + matv16(b0, b1, b2, b3, w) + h1;
        acc += fmaxf(m0, 0.f) + fmaxf(m1, 0.f);
    }
    if (p < p1) {
        long q0 = GATH ? (long)p : (long)perm[p];
        const float4* ra = (const float4*)(eaG + q0 * EDIM);
        int s0 = src_perm[p];
        float m0 = bj + matv16(ra[0], ra[1], ra[2], ra[3], w) + h[(long)s0 * HID + j];
        acc += fmaxf(m0, 0.f);
    }
    t[(long)node * HID + j] = acc;
}

// ================= GEMM: 128x128 tile, 8x8 per thread, fused pre-BN / post-stats =================
template<int K, bool PRE_BN, bool POST_STATS>
__global__ __launch_bounds__(256) void gemm_kernel(
    const float* __restrict__ A, const float* __restrict__ W, const float* __restrict__ bias,
    const float* __restrict__ preStats, const float* __restrict__ preG, const float* __restrict__ preB,
    float* __restrict__ C, float* __restrict__ postStats, int Nrows, float invN)
{
    __shared__ __align__(16) float At[32 * 132];   // [k][r] transposed, padded
    __shared__ __align__(16) float Wl[32 * 128];   // [k][c]
    __shared__ float sc[PRE_BN ? K : 1], sb[PRE_BN ? K : 1];
    int tid = threadIdx.x;
    int rbase = blockIdx.x * 128;
    if (PRE_BN) {
        if (tid < K) {
            float mean = preStats[tid] * invN;
            float var = preStats[K + tid] * invN - mean * mean;
            float rstd = rsqrtf(var + 1e-5f);
            float g = preG[tid];
            sc[tid] = rstd * g;
            sb[tid] = preB[tid] - mean * rstd * g;
        }
        __syncthreads();
    }
    int tx = tid & 15, ty = tid >> 4;
    int c0 = tx * 8, r0 = ty * 8;
    float acc[8][8];
#pragma unroll
    for (int i = 0; i < 8; ++i)
#pragma unroll
        for (int jj = 0; jj < 8; ++jj) acc[i][jj] = 0.f;

    for (int k0 = 0; k0 < K; k0 += 32) {
#pragma unroll
        for (int i = 0; i < 4; ++i) {
            int idx = tid + i * 256;           // 1024 float4s: 128 rows x 8
            int r = idx >> 3, kk = (idx & 7) * 4;
            int gr = rbase + r;
            float4 v = make_float4(0.f, 0.f, 0.f, 0.f);
            if (gr < Nrows) v = *(const float4*)&A[(long)gr * K + k0 + kk];
            if (PRE_BN) {
                v.x = fmaxf(v.x * sc[k0 + kk]     + sb[k0 + kk],     0.f);
                v.y = fmaxf(v.y * sc[k0 + kk + 1] + sb[k0 + kk + 1], 0.f);
                v.z = fmaxf(v.z * sc[k0 + kk + 2] + sb[k0 + kk + 2], 0.f);
                v.w = fmaxf(v.w * sc[k0 + kk + 3] + sb[k0 + kk + 3], 0.f);
            }
            At[(kk + 0) * 132 + r] = v.x;
            At[(kk + 1) * 132 + r] = v.y;
            At[(kk + 2) * 132 + r] = v.z;
            At[(kk + 3) * 132 + r] = v.w;
        }
#pragma unroll
        for (int i = 0; i < 4; ++i) {
            int idx = tid + i * 256;           // 1024 float4s: 32 k x 32
            int kk = idx >> 5, c4 = (idx & 31) * 4;
            *(float4*)&Wl[kk * 128 + c4] = *(const float4*)&W[(long)(k0 + kk) * HID + c4];
        }
        __syncthreads();
#pragma unroll
        for (int k = 0; k < 32; ++k) {
            float4 a0 = *(const float4*)&At[k * 132 + r0];
            float4 a1 = *(const float4*)&At[k * 132 + r0 + 4];
            float4 w0 = *(const float4*)&Wl[k * 128 + c0];
            float4 w1 = *(const float4*)&Wl[k * 128 + c0 + 4];
            float av[8] = {a0.x, a0.y, a0.z, a0.w, a1.x, a1.y, a1.z, a1.w};
            float wv[8] = {w0.x, w0.y, w0.z, w0.w, w1.x, w1.y, w1.z, w1.w};
#pragma unroll
            for (int i = 0; i < 8; ++i)
#pragma unroll
                for (int jj = 0; jj < 8; ++jj) acc[i][jj] += av[i] * wv[jj];
        }
        __syncthreads();
    }

    float4 bq0 = *(const float4*)&bias[c0];
    float4 bq1 = *(const float4*)&bias[c0 + 4];
    float bv[8] = {bq0.x, bq0.y, bq0.z, bq0.w, bq1.x, bq1.y, bq1.z, bq1.w};
    float s[8], q[8];
#pragma unroll
    for (int jj = 0; jj < 8; ++jj) { s[jj] = 0.f; q[jj] = 0.f; }
#pragma unroll
    for (int i = 0; i < 8; ++i) {
        int gr = rbase + r0 + i;
        if (gr < Nrows) {
            float outv[8];
#pragma unroll
            for (int jj = 0; jj < 8; ++jj) {
                outv[jj] = acc[i][jj] + bv[jj];
                if (POST_STATS) { s[jj] += outv[jj]; q[jj] += outv[jj] * outv[jj]; }
            }
            *(float4*)&C[(long)gr * HID + c0]     = make_float4(outv[0], outv[1], outv[2], outv[3]);
            *(float4*)&C[(long)gr * HID + c0 + 4] = make_float4(outv[4], outv[5], outv[6], outv[7]);
        }
    }
    if (POST_STATS) {
        float* redS = At;   // reuse (last barrier already passed)
        float* redQ = Wl;
#pragma unroll
        for (int jj = 0; jj < 8; ++jj) {
            redS[ty * 128 + c0 + jj] = s[jj];
            redQ[ty * 128 + c0 + jj] = q[jj];
        }
        __syncthreads();
        if (tid < 128) {
            float S = 0.f, Q = 0.f;
#pragma unroll
            for (int g2 = 0; g2 < 16; ++g2) { S += redS[g2 * 128 + tid]; Q += redQ[g2 * 128 + tid]; }
            atomicAdd(&postStats[tid], S);
            atomicAdd(&postStats[128 + tid], Q);
        }
    }
}

// ================= BN apply + ReLU =================
__global__ void bn_apply(const float* __restrict__ X, float* __restrict__ out,
                         const float* __restrict__ stats, const float* __restrict__ g,
                         const float* __restrict__ b, long total, float invN)
{
    long idx = (long)blockIdx.x * blockDim.x + threadIdx.x;
    if (idx >= total) return;
    int ch = (int)(idx & 127);
    float mean = stats[ch] * invN;
    float var = stats[128 + ch] * invN - mean * mean;
    float rstd = rsqrtf(var + 1e-5f);
    float v = (X[idx] - mean) * rstd * g[ch] + b[ch];
    out[idx] = fmaxf(v, 0.f);
}

// ================= segment boundaries (batch sorted) =================
__global__ void starts_kernel(const int* __restrict__ batch, int* __restrict__ starts,
                              int Nn, int Gn)
{
    int g = blockIdx.x * blockDim.x + threadIdx.x;
    if (g > Gn) return;
    int lo = 0, hi = Nn;
    while (lo < hi) { int mid = (lo + hi) >> 1; if (batch[mid] < g) lo = mid + 1; else hi = mid; }
    starts[g] = lo;
}

// ============ per-layer pooling ============
__global__ void pool_kernel(const float* __restrict__ h, const int* __restrict__ starts,
                            float* __restrict__ z, int l)
{
    int g = blockIdx.x;
    int tid = threadIdx.x;
    int j = tid & 127, half = tid >> 7;
    int s = starts[g], e = starts[g + 1];
    float sum = 0.f, mx = 0.f;  // h >= 0 after ReLU
    for (int n = s + half; n < e; n += 2) {
        float v = h[(long)n * HID + j];
        sum += v; mx = fmaxf(mx, v);
    }
    __shared__ float ls[256], lm[256];
    ls[tid] = sum; lm[tid] = mx;
    __syncthreads();
    if (tid < 128) {
        sum = ls[tid] + ls[tid + 128];
        mx = fmaxf(lm[tid], lm[tid + 128]);
        float cnt = (float)(e - s);
        z[(long)g * 768 + l * 128 + tid] = sum / fmaxf(cnt, 1.f);
        z[(long)g * 768 + 384 + l * 128 + tid] = mx;
    }
}

// ================= head =================
__global__ void head_gemm1(const float* __restrict__ z, const float* __restrict__ W,
                           const float* __restrict__ bias, float* __restrict__ zr)
{
    __shared__ __align__(16) float zl[768];
    int g = blockIdx.x, j = threadIdx.x;
    for (int i = j; i < 768; i += 128) zl[i] = z[(long)g * 768 + i];
    __syncthreads();
    float acc = bias[j];
    for (int k = 0; k < 768; k += 4) {
        float4 a4 = *(const float4*)&zl[k];
        acc += a4.x * W[k * 128 + j] + a4.y * W[(k + 1) * 128 + j]
             + a4.z * W[(k + 2) * 128 + j] + a4.w * W[(k + 3) * 128 + j];
    }
    zr[(long)g * 128 + j] = acc;
}

__global__ void head_stats(const float* __restrict__ zr, float* __restrict__ ms, int Gn)
{
    int j = threadIdx.x;  // 128 threads
    float sum = 0.f, sq = 0.f;
    for (int r = 0; r < Gn; ++r) { float v = zr[(long)r * 128 + j]; sum += v; sq += v * v; }
    float mean = sum / (float)Gn;
    float var = sq / (float)Gn - mean * mean;
    ms[j] = mean;
    ms[128 + j] = rsqrtf(var + 1e-5f);
}

__global__ void head_final(const float* __restrict__ zr, const float* __restrict__ ms,
                           const float* __restrict__ hg, const float* __restrict__ hb,
                           const float* __restrict__ W2, const float* __restrict__ b2,
                           float* __restrict__ out)
{
    int g = blockIdx.x, j = threadIdx.x;
    float v = zr[(long)g * 128 + j];
    v = (v - ms[j]) * ms[128 + j] * hg[j] + hb[j];
    v = fmaxf(v, 0.f);
    float p = v * W2[j];
#pragma unroll
    for (int off = 32; off > 0; off >>= 1) p += __shfl_down(p, off, 64);
    __shared__ float partial[2];
    if ((j & 63) == 0) partial[j >> 6] = p;
    __syncthreads();
    if (j == 0) out[g] = partial[0] + partial[1] + b2[0];
}

extern "C" void kernel_launch(void* const* d_in, const int* in_sizes, int n_in,
                              void* d_out, int out_size, void* d_ws, size_t ws_size,
                              hipStream_t stream)
{
    const float* x         = (const float*)d_in[0];
    const float* edge_attr = (const float*)d_in[1];
    const int*   src       = (const int*)d_in[2];
    const int*   dst       = (const int*)d_in[3];
    const int*   batch     = (const int*)d_in[4];
    const float* Wp        = (const float*)d_in[5];
    const float* bp        = (const float*)d_in[6];
    const float* conv_We   = (const float*)d_in[7];
    const float* conv_be   = (const float*)d_in[8];
    const float* conv_W1   = (const float*)d_in[9];
    const float* conv_b1   = (const float*)d_in[10];
    const float* conv_g1   = (const float*)d_in[11];
    const float* conv_bt1  = (const float*)d_in[12];
    const float* conv_W2   = (const float*)d_in[13];
    const float* conv_b2   = (const float*)d_in[14];
    const float* bn_g      = (const float*)d_in[15];
    const float* bn_b      = (const float*)d_in[16];
    const float* head_W1   = (const float*)d_in[17];
    const float* head_b1   = (const float*)d_in[18];
    const float* head_g    = (const float*)d_in[19];
    const float* head_bt   = (const float*)d_in[20];
    const float* head_W2   = (const float*)d_in[21];
    const float* head_b2   = (const float*)d_in[22];

    const int N = in_sizes[4];            // 50000
    const int E = in_sizes[2];            // 800000
    const int G = out_size;               // 256
    const int L = 3;

    // ---- workspace layout ----
    float* h        = (float*)d_ws;                  // N*128
    float* t        = h + (long)N * HID;             // N*128
    float* z        = t + (long)N * HID;             // G*768
    float* zr       = z + (long)G * 768;             // G*128
    float* statsAll = zr + (long)G * HID;            // 7*256
    int*   starts   = (int*)(statsAll + 7 * 256);    // G+1
    int*   row_start= starts + (G + 1);              // N+1
    int*   cursor   = row_start + (N + 1);           // N
    int*   deg      = cursor + N;                    // N
    int*   bsum     = deg + N;                       // 256
    int*   perm     = bsum + 256;                    // E
    int*   src_perm = perm + E;                      // E
    // optional gathered edge_attr (aligned up to 16B)
    size_t base_end = (size_t)((char*)(src_perm + E) - (char*)d_ws);
    size_t ea_off = (base_end + 15) & ~(size_t)15;
    bool gath = (ea_off + (size_t)E * EDIM * sizeof(float)) <= ws_size;
    float* ea_perm = (float*)((char*)d_ws + ea_off);
    float* ms = statsAll + 6 * 256;

    (void)n_in;

    const long totalNH = (long)N * HID;
    const float invN = 1.0f / (float)N;
    const int nb = (N + 255) / 256;
    const int gemmBlocks = (N + 127) / 128;
    const int bnApplyBlocks = (int)((totalNH + 255) / 256);

    // ---- CSR build ----
    hipMemsetAsync(deg, 0, (size_t)N * sizeof(int), stream);
    hist_kernel<<<(E + 255) / 256, 256, 0, stream>>>(dst, deg, E);
    block_sum_kernel<<<nb, 256, 0, stream>>>(deg, bsum, N);
    bsum_scan_kernel<<<1, 256, 0, stream>>>(bsum, nb, &row_start[N]);
    block_scan_kernel<<<nb, 256, 0, stream>>>(deg, bsum, row_start, cursor, N);
    scatter_kernel<<<(E + 255) / 256, 256, 0, stream>>>(src, dst, cursor, perm, src_perm, E);
    if (gath)
        gather_ea_kernel<<<(E * 4 + 255) / 256, 256, 0, stream>>>(edge_attr, perm, ea_perm, E);
    starts_kernel<<<1, 512, 0, stream>>>(batch, starts, N, G);
    hipMemsetAsync(statsAll, 0, 7 * 256 * sizeof(float), stream);

    // h = x @ Wp + bp
    gemm_kernel<64, false, false><<<gemmBlocks, 256, 0, stream>>>(
        x, Wp, bp, nullptr, nullptr, nullptr, h, nullptr, N, invN);

    for (int l = 0; l < L; ++l) {
        float* sI = statsAll + l * 512;
        float* sO = sI + 256;
        if (gath)
            aggregate_kernel<true><<<(N + 1) / 2, 256, 0, stream>>>(
                h, ea_perm, perm, src_perm, row_start,
                conv_We + (long)l * EDIM * HID, conv_be + l * HID, t, N);
        else
            aggregate_kernel<false><<<(N + 1) / 2, 256, 0, stream>>>(
                h, edge_attr, perm, src_perm, row_start,
                conv_We + (long)l * EDIM * HID, conv_be + l * HID, t, N);
        // t = t @ W1 + b1, fused inner-BN stats
        gemm_kernel<128, false, true><<<gemmBlocks, 256, 0, stream>>>(
            t, conv_W1 + (long)l * HID * HID, conv_b1 + l * HID,
            nullptr, nullptr, nullptr, t, sI, N, invN);
        // t = relu(BN_inner(t)) @ W2 + b2, fused outer-BN stats
        gemm_kernel<128, true, true><<<gemmBlocks, 256, 0, stream>>>(
            t, conv_W2 + (long)l * HID * HID, conv_b2 + l * HID,
            sI, conv_g1 + l * HID, conv_bt1 + l * HID, t, sO, N, invN);
        // h = relu(BN_outer(t))
        bn_apply<<<bnApplyBlocks, 256, 0, stream>>>(
            t, h, sO, bn_g + l * HID, bn_b + l * HID, totalNH, invN);
        pool_kernel<<<G, 256, 0, stream>>>(h, starts, z, l);
    }

    head_gemm1<<<G, 128, 0, stream>>>(z, head_W1, head_b1, zr);
    head_stats<<<1, 128, 0, stream>>>(zr, ms, G);
    head_final<<<G, 128, 0, stream>>>(zr, ms, head_g, head_bt, head_W2, head_b2, (float*)d_out);
}

// Round 4
// 1256.358 us; speedup vs baseline: 1.5643x; 1.0761x over previous
//
#include <hip/hip_runtime.h>
#include <hip/hip_bf16.h>

#define HID 128
#define EDIM 16

// ================= CSR build =================
__global__ void hist_kernel(const int* __restrict__ dst, int* __restrict__ deg, int E)
{
    int e = blockIdx.x * 256 + threadIdx.x;
    if (e < E) atomicAdd(&deg[dst[e]], 1);
}

__global__ void block_sum_kernel(const int* __restrict__ deg, int* __restrict__ bsum, int Nn)
{
    int i = blockIdx.x * 256 + threadIdx.x;
    int v = (i < Nn) ? deg[i] : 0;
#pragma unroll
    for (int off = 32; off > 0; off >>= 1) v += __shfl_down(v, off, 64);
    __shared__ int ws[4];
    if ((threadIdx.x & 63) == 0) ws[threadIdx.x >> 6] = v;
    __syncthreads();
    if (threadIdx.x == 0) bsum[blockIdx.x] = ws[0] + ws[1] + ws[2] + ws[3];
}

__global__ void bsum_scan_kernel(int* bsum, int nb, int* total_out)
{
    __shared__ int sh[256];
    int tid = threadIdx.x;
    int v = (tid < nb) ? bsum[tid] : 0;
    sh[tid] = v;
    __syncthreads();
    for (int off = 1; off < 256; off <<= 1) {
        int tv = (tid >= off) ? sh[tid - off] : 0;
        __syncthreads();
        sh[tid] += tv;
        __syncthreads();
    }
    if (tid < nb) bsum[tid] = sh[tid] - v;
    if (tid == 255) *total_out = sh[255];
}

__global__ void block_scan_kernel(const int* __restrict__ deg, const int* __restrict__ bsum,
                                  int* __restrict__ row_start, int* __restrict__ cursor, int Nn)
{
    __shared__ int sh[256];
    int tid = threadIdx.x;
    int i = blockIdx.x * 256 + tid;
    int v = (i < Nn) ? deg[i] : 0;
    sh[tid] = v;
    __syncthreads();
    for (int off = 1; off < 256; off <<= 1) {
        int tv = (tid >= off) ? sh[tid - off] : 0;
        __syncthreads();
        sh[tid] += tv;
        __syncthreads();
    }
    if (i < Nn) {
        int excl = sh[tid] - v + bsum[blockIdx.x];
        row_start[i] = excl;
        cursor[i] = excl;
    }
}

__global__ void scatter_kernel(const int* __restrict__ src, const int* __restrict__ dst,
                               int* cursor, int* __restrict__ perm,
                               int* __restrict__ src_perm, int E)
{
    int e = blockIdx.x * 256 + threadIdx.x;
    if (e >= E) return;
    int pos = atomicAdd(&cursor[dst[e]], 1);
    perm[pos] = e;
    src_perm[pos] = src[e];
}

__global__ void gather_ea_kernel(const float* __restrict__ ea, const int* __restrict__ perm,
                                 float* __restrict__ ea_perm, int E)
{
    int idx = blockIdx.x * 256 + threadIdx.x;
    int p = idx >> 2, c = (idx & 3) * 4;
    if (p >= E) return;
    int e = perm[p];
    *(float4*)&ea_perm[(long)p * EDIM + c] = *(const float4*)&ea[(long)e * EDIM + c];
}

// ====== Node-centric aggregation: 1 wave per node, 2 channels/lane, x4 edge pipeline ======
__device__ __forceinline__ void matv2(const float4& a0, const float4& a1,
                                      const float4& a2, const float4& a3,
                                      const float2* __restrict__ w,
                                      float& m0, float& m1)
{
    m0 += a0.x*w[0].x + a0.y*w[1].x + a0.z*w[2].x + a0.w*w[3].x
        + a1.x*w[4].x + a1.y*w[5].x + a1.z*w[6].x + a1.w*w[7].x
        + a2.x*w[8].x + a2.y*w[9].x + a2.z*w[10].x + a2.w*w[11].x
        + a3.x*w[12].x + a3.y*w[13].x + a3.z*w[14].x + a3.w*w[15].x;
    m1 += a0.x*w[0].y + a0.y*w[1].y + a0.z*w[2].y + a0.w*w[3].y
        + a1.x*w[4].y + a1.y*w[5].y + a1.z*w[6].y + a1.w*w[7].y
        + a2.x*w[8].y + a2.y*w[9].y + a2.z*w[10].y + a2.w*w[11].y
        + a3.x*w[12].y + a3.y*w[13].y + a3.z*w[14].y + a3.w*w[15].y;
}

template<bool GATH>
__global__ __launch_bounds__(256) void aggregate_kernel(
    const float* __restrict__ h, const float* __restrict__ eaG,
    const int* __restrict__ perm, const int* __restrict__ src_perm,
    const int* __restrict__ row_start,
    const float* __restrict__ We, const float* __restrict__ be,
    float* __restrict__ t, int Nn)
{
    int tid = threadIdx.x;
    int lane = tid & 63;
    int c = lane * 2;                       // channels c, c+1
    float2 w[16];
#pragma unroll
    for (int k = 0; k < 16; ++k) w[k] = *(const float2*)&We[k * HID + c];
    float2 bj = *(const float2*)&be[c];
    int node = blockIdx.x * 4 + (tid >> 6);
    if (node >= Nn) return;
    float2 acc = *(const float2*)&h[(long)node * HID + c];
    int p0 = row_start[node], p1 = row_start[node + 1];
    int p = p0;
    for (; p + 3 < p1; p += 4) {
        int s0 = src_perm[p], s1 = src_perm[p + 1], s2 = src_perm[p + 2], s3 = src_perm[p + 3];
        float2 h0 = *(const float2*)&h[(long)s0 * HID + c];
        float2 h1 = *(const float2*)&h[(long)s1 * HID + c];
        float2 h2 = *(const float2*)&h[(long)s2 * HID + c];
        float2 h3 = *(const float2*)&h[(long)s3 * HID + c];
        long q0 = GATH ? (long)p     : (long)perm[p];
        long q1 = GATH ? (long)(p+1) : (long)perm[p + 1];
        long q2 = GATH ? (long)(p+2) : (long)perm[p + 2];
        long q3 = GATH ? (long)(p+3) : (long)perm[p + 3];
        const float4* e0 = (const float4*)(eaG + q0 * EDIM);
        const float4* e1 = (const float4*)(eaG + q1 * EDIM);
        const float4* e2 = (const float4*)(eaG + q2 * EDIM);
        const float4* e3 = (const float4*)(eaG + q3 * EDIM);
        float4 a00 = e0[0], a01 = e0[1], a02 = e0[2], a03 = e0[3];
        float4 a10 = e1[0], a11 = e1[1], a12 = e1[2], a13 = e1[3];
        float4 a20 = e2[0], a21 = e2[1], a22 = e2[2], a23 = e2[3];
        float4 a30 = e3[0], a31 = e3[1], a32 = e3[2], a33 = e3[3];
        float m00 = bj.x + h0.x, m01 = bj.y + h0.y;
        float m10 = bj.x + h1.x, m11 = bj.y + h1.y;
        float m20 = bj.x + h2.x, m21 = bj.y + h2.y;
        float m30 = bj.x + h3.x, m31 = bj.y + h3.y;
        matv2(a00, a01, a02, a03, w, m00, m01);
        matv2(a10, a11, a12, a13, w, m10, m11);
        matv2(a20, a21, a22, a23, w, m20, m21);
        matv2(a30, a31, a32, a33, w, m30, m31);
        acc.x += fmaxf(m00, 0.f) + fmaxf(m10, 0.f) + fmaxf(m20, 0.f) + fmaxf(m30, 0.f);
        acc.y += fmaxf(m01, 0.f) + fmaxf(m11, 0.f) + fmaxf(m21, 0.f) + fmaxf(m31, 0.f);
    }
    for (; p < p1; ++p) {
        int s0 = src_perm[p];
        float2 h0 = *(const float2*)&h[(long)s0 * HID + c];
        long q0 = GATH ? (long)p : (long)perm[p];
        const float4* e0 = (const float4*)(eaG + q0 * EDIM);
        float4 a0 = e0[0], a1 = e0[1], a2 = e0[2], a3 = e0[3];
        float m0 = bj.x + h0.x, m1 = bj.y + h0.y;
        matv2(a0, a1, a2, a3, w, m0, m1);
        acc.x += fmaxf(m0, 0.f);
        acc.y += fmaxf(m1, 0.f);
    }
    *(float2*)&t[(long)node * HID + c] = acc;
}

// ================= GEMM: 128x128 tile, 8x8 per thread, fused pre-BN / post-stats =================
template<int K, bool PRE_BN, bool POST_STATS>
__global__ __launch_bounds__(256) void gemm_kernel(
    const float* __restrict__ A, const float* __restrict__ W, const float* __restrict__ bias,
    const float* __restrict__ preStats, const float* __restrict__ preG, const float* __restrict__ preB,
    float* __restrict__ C, float* __restrict__ postStats, int Nrows, float invN)
{
    __shared__ __align__(16) float At[32 * 132];   // [k][r] transposed, padded
    __shared__ __align__(16) float Wl[32 * 128];   // [k][c]
    __shared__ float sc[PRE_BN ? K : 1], sb[PRE_BN ? K : 1];
    int tid = threadIdx.x;
    int rbase = blockIdx.x * 128;
    if (PRE_BN) {
        if (tid < K) {
            float mean = preStats[tid] * invN;
            float var = preStats[K + tid] * invN - mean * mean;
            float rstd = rsqrtf(var + 1e-5f);
            float g = preG[tid];
            sc[tid] = rstd * g;
            sb[tid] = preB[tid] - mean * rstd * g;
        }
        __syncthreads();
    }
    int tx = tid & 15, ty = tid >> 4;
    int c0 = tx * 8, r0 = ty * 8;
    float acc[8][8];
#pragma unroll
    for (int i = 0; i < 8; ++i)
#pragma unroll
        for (int jj = 0; jj < 8; ++jj) acc[i][jj] = 0.f;

    for (int k0 = 0; k0 < K; k0 += 32) {
#pragma unroll
        for (int i = 0; i < 4; ++i) {
            int idx = tid + i * 256;           // 1024 float4s: 128 rows x 8
            int r = idx >> 3, kk = (idx & 7) * 4;
            int gr = rbase + r;
            float4 v = make_float4(0.f, 0.f, 0.f, 0.f);
            if (gr < Nrows) v = *(const float4*)&A[(long)gr * K + k0 + kk];
            if (PRE_BN) {
                v.x = fmaxf(v.x * sc[k0 + kk]     + sb[k0 + kk],     0.f);
                v.y = fmaxf(v.y * sc[k0 + kk + 1] + sb[k0 + kk + 1], 0.f);
                v.z = fmaxf(v.z * sc[k0 + kk + 2] + sb[k0 + kk + 2], 0.f);
                v.w = fmaxf(v.w * sc[k0 + kk + 3] + sb[k0 + kk + 3], 0.f);
            }
            At[(kk + 0) * 132 + r] = v.x;
            At[(kk + 1) * 132 + r] = v.y;
            At[(kk + 2) * 132 + r] = v.z;
            At[(kk + 3) * 132 + r] = v.w;
        }
#pragma unroll
        for (int i = 0; i < 4; ++i) {
            int idx = tid + i * 256;           // 1024 float4s: 32 k x 32
            int kk = idx >> 5, c4 = (idx & 31) * 4;
            *(float4*)&Wl[kk * 128 + c4] = *(const float4*)&W[(long)(k0 + kk) * HID + c4];
        }
        __syncthreads();
#pragma unroll
        for (int k = 0; k < 32; ++k) {
            float4 a0 = *(const float4*)&At[k * 132 + r0];
            float4 a1 = *(const float4*)&At[k * 132 + r0 + 4];
            float4 w0 = *(const float4*)&Wl[k * 128 + c0];
            float4 w1 = *(const float4*)&Wl[k * 128 + c0 + 4];
            float av[8] = {a0.x, a0.y, a0.z, a0.w, a1.x, a1.y, a1.z, a1.w};
            float wv[8] = {w0.x, w0.y, w0.z, w0.w, w1.x, w1.y, w1.z, w1.w};
#pragma unroll
            for (int i = 0; i < 8; ++i)
#pragma unroll
                for (int jj = 0; jj < 8; ++jj) acc[i][jj] += av[i] * wv[jj];
        }
        __syncthreads();
    }

    float4 bq0 = *(const float4*)&bias[c0];
    float4 bq1 = *(const float4*)&bias[c0 + 4];
    float bv[8] = {bq0.x, bq0.y, bq0.z, bq0.w, bq1.x, bq1.y, bq1.z, bq1.w};
    float s[8], q[8];
#pragma unroll
    for (int jj = 0; jj < 8; ++jj) { s[jj] = 0.f; q[jj] = 0.f; }
#pragma unroll
    for (int i = 0; i < 8; ++i) {
        int gr = rbase + r0 + i;
        if (gr < Nrows) {
            float outv[8];
#pragma unroll
            for (int jj = 0; jj < 8; ++jj) {
                outv[jj] = acc[i][jj] + bv[jj];
                if (POST_STATS) { s[jj] += outv[jj]; q[jj] += outv[jj] * outv[jj]; }
            }
            *(float4*)&C[(long)gr * HID + c0]     = make_float4(outv[0], outv[1], outv[2], outv[3]);
            *(float4*)&C[(long)gr * HID + c0 + 4] = make_float4(outv[4], outv[5], outv[6], outv[7]);
        }
    }
    if (POST_STATS) {
        float* redS = At;   // reuse (k-loop's final barrier already passed)
        float* redQ = Wl;
#pragma unroll
        for (int jj = 0; jj < 8; ++jj) {
            redS[ty * 128 + c0 + jj] = s[jj];
            redQ[ty * 128 + c0 + jj] = q[jj];
        }
        __syncthreads();
        if (tid < 128) {
            float S = 0.f, Q = 0.f;
#pragma unroll
            for (int g2 = 0; g2 < 16; ++g2) { S += redS[g2 * 128 + tid]; Q += redQ[g2 * 128 + tid]; }
            atomicAdd(&postStats[tid], S);
            atomicAdd(&postStats[128 + tid], Q);
        }
    }
}

// ================= fused BN apply + ReLU + per-graph pooling =================
// grid = G blocks (one per graph), 256 threads (2 row-walkers x 128 channels)
__global__ void bn_apply_pool(const float* __restrict__ X, float* __restrict__ h,
                              const float* __restrict__ stats, const float* __restrict__ g,
                              const float* __restrict__ b, const int* __restrict__ starts,
                              float* __restrict__ z, int l, float invN)
{
    int gph = blockIdx.x;
    int tid = threadIdx.x;
    int j = tid & 127, half = tid >> 7;
    float mean = stats[j] * invN;
    float var = stats[128 + j] * invN - mean * mean;
    float rstd = rsqrtf(var + 1e-5f);
    float gg = g[j];
    float scale = rstd * gg;
    float shift = b[j] - mean * rstd * gg;
    int s = starts[gph], e = starts[gph + 1];
    float sum = 0.f, mx = 0.f;                 // outputs >= 0 after ReLU
    for (int n = s + half; n < e; n += 2) {
        float v = fmaxf(X[(long)n * HID + j] * scale + shift, 0.f);
        h[(long)n * HID + j] = v;
        sum += v; mx = fmaxf(mx, v);
    }
    __shared__ float ls[256], lm[256];
    ls[tid] = sum; lm[tid] = mx;
    __syncthreads();
    if (tid < 128) {
        sum = ls[tid] + ls[tid + 128];
        mx = fmaxf(lm[tid], lm[tid + 128]);
        float cnt = (float)(e - s);
        z[(long)gph * 768 + l * 128 + tid] = sum / fmaxf(cnt, 1.f);
        z[(long)gph * 768 + 384 + l * 128 + tid] = mx;
    }
}

// ================= segment boundaries (batch sorted) =================
__global__ void starts_kernel(const int* __restrict__ batch, int* __restrict__ starts,
                              int Nn, int Gn)
{
    int g = blockIdx.x * blockDim.x + threadIdx.x;
    if (g > Gn) return;
    int lo = 0, hi = Nn;
    while (lo < hi) { int mid = (lo + hi) >> 1; if (batch[mid] < g) lo = mid + 1; else hi = mid; }
    starts[g] = lo;
}

// ================= head =================
__global__ void head_gemm1(const float* __restrict__ z, const float* __restrict__ W,
                           const float* __restrict__ bias, float* __restrict__ zr)
{
    __shared__ __align__(16) float zl[768];
    int g = blockIdx.x, j = threadIdx.x;
    for (int i = j; i < 768; i += 128) zl[i] = z[(long)g * 768 + i];
    __syncthreads();
    float acc = bias[j];
    for (int k = 0; k < 768; k += 4) {
        float4 a4 = *(const float4*)&zl[k];
        acc += a4.x * W[k * 128 + j] + a4.y * W[(k + 1) * 128 + j]
             + a4.z * W[(k + 2) * 128 + j] + a4.w * W[(k + 3) * 128 + j];
    }
    zr[(long)g * 128 + j] = acc;
}

__global__ void head_stats(const float* __restrict__ zr, float* __restrict__ ms, int Gn)
{
    int j = threadIdx.x;  // 128 threads
    float sum = 0.f, sq = 0.f;
    for (int r = 0; r < Gn; ++r) { float v = zr[(long)r * 128 + j]; sum += v; sq += v * v; }
    float mean = sum / (float)Gn;
    float var = sq / (float)Gn - mean * mean;
    ms[j] = mean;
    ms[128 + j] = rsqrtf(var + 1e-5f);
}

__global__ void head_final(const float* __restrict__ zr, const float* __restrict__ ms,
                           const float* __restrict__ hg, const float* __restrict__ hb,
                           const float* __restrict__ W2, const float* __restrict__ b2,
                           float* __restrict__ out)
{
    int g = blockIdx.x, j = threadIdx.x;
    float v = zr[(long)g * 128 + j];
    v = (v - ms[j]) * ms[128 + j] * hg[j] + hb[j];
    v = fmaxf(v, 0.f);
    float p = v * W2[j];
#pragma unroll
    for (int off = 32; off > 0; off >>= 1) p += __shfl_down(p, off, 64);
    __shared__ float partial[2];
    if ((j & 63) == 0) partial[j >> 6] = p;
    __syncthreads();
    if (j == 0) out[g] = partial[0] + partial[1] + b2[0];
}

extern "C" void kernel_launch(void* const* d_in, const int* in_sizes, int n_in,
                              void* d_out, int out_size, void* d_ws, size_t ws_size,
                              hipStream_t stream)
{
    const float* x         = (const float*)d_in[0];
    const float* edge_attr = (const float*)d_in[1];
    const int*   src       = (const int*)d_in[2];
    const int*   dst       = (const int*)d_in[3];
    const int*   batch     = (const int*)d_in[4];
    const float* Wp        = (const float*)d_in[5];
    const float* bp        = (const float*)d_in[6];
    const float* conv_We   = (const float*)d_in[7];
    const float* conv_be   = (const float*)d_in[8];
    const float* conv_W1   = (const float*)d_in[9];
    const float* conv_b1   = (const float*)d_in[10];
    const float* conv_g1   = (const float*)d_in[11];
    const float* conv_bt1  = (const float*)d_in[12];
    const float* conv_W2   = (const float*)d_in[13];
    const float* conv_b2   = (const float*)d_in[14];
    const float* bn_g      = (const float*)d_in[15];
    const float* bn_b      = (const float*)d_in[16];
    const float* head_W1   = (const float*)d_in[17];
    const float* head_b1   = (const float*)d_in[18];
    const float* head_g    = (const float*)d_in[19];
    const float* head_bt   = (const float*)d_in[20];
    const float* head_W2   = (const float*)d_in[21];
    const float* head_b2   = (const float*)d_in[22];

    const int N = in_sizes[4];            // 50000
    const int E = in_sizes[2];            // 800000
    const int G = out_size;               // 256
    const int L = 3;

    // ---- workspace layout ----
    float* h        = (float*)d_ws;                  // N*128
    float* t        = h + (long)N * HID;             // N*128
    float* z        = t + (long)N * HID;             // G*768
    float* zr       = z + (long)G * 768;             // G*128
    float* statsAll = zr + (long)G * HID;            // 7*256
    int*   starts   = (int*)(statsAll + 7 * 256);    // G+1
    int*   row_start= starts + (G + 1);              // N+1
    int*   cursor   = row_start + (N + 1);           // N
    int*   deg      = cursor + N;                    // N
    int*   bsum     = deg + N;                       // 256
    int*   perm     = bsum + 256;                    // E
    int*   src_perm = perm + E;                      // E
    size_t base_end = (size_t)((char*)(src_perm + E) - (char*)d_ws);
    size_t ea_off = (base_end + 15) & ~(size_t)15;
    bool gath = (ea_off + (size_t)E * EDIM * sizeof(float)) <= ws_size;
    float* ea_perm = (float*)((char*)d_ws + ea_off);
    float* ms = statsAll + 6 * 256;

    (void)n_in;

    const float invN = 1.0f / (float)N;
    const float invG = 1.0f;  // unused
    (void)invG;
    const int nb = (N + 255) / 256;
    const int gemmBlocks = (N + 127) / 128;

    // ---- CSR build ----
    hipMemsetAsync(deg, 0, (size_t)N * sizeof(int), stream);
    hist_kernel<<<(E + 255) / 256, 256, 0, stream>>>(dst, deg, E);
    block_sum_kernel<<<nb, 256, 0, stream>>>(deg, bsum, N);
    bsum_scan_kernel<<<1, 256, 0, stream>>>(bsum, nb, &row_start[N]);
    block_scan_kernel<<<nb, 256, 0, stream>>>(deg, bsum, row_start, cursor, N);
    scatter_kernel<<<(E + 255) / 256, 256, 0, stream>>>(src, dst, cursor, perm, src_perm, E);
    if (gath)
        gather_ea_kernel<<<(E * 4 + 255) / 256, 256, 0, stream>>>(edge_attr, perm, ea_perm, E);
    starts_kernel<<<1, 512, 0, stream>>>(batch, starts, N, G);
    hipMemsetAsync(statsAll, 0, 7 * 256 * sizeof(float), stream);

    // h = x @ Wp + bp
    gemm_kernel<64, false, false><<<gemmBlocks, 256, 0, stream>>>(
        x, Wp, bp, nullptr, nullptr, nullptr, h, nullptr, N, invN);

    for (int l = 0; l < L; ++l) {
        float* sI = statsAll + l * 512;
        float* sO = sI + 256;
        if (gath)
            aggregate_kernel<true><<<(N + 3) / 4, 256, 0, stream>>>(
                h, ea_perm, perm, src_perm, row_start,
                conv_We + (long)l * EDIM * HID, conv_be + l * HID, t, N);
        else
            aggregate_kernel<false><<<(N + 3) / 4, 256, 0, stream>>>(
                h, edge_attr, perm, src_perm, row_start,
                conv_We + (long)l * EDIM * HID, conv_be + l * HID, t, N);
        // t = t @ W1 + b1, fused inner-BN stats
        gemm_kernel<128, false, true><<<gemmBlocks, 256, 0, stream>>>(
            t, conv_W1 + (long)l * HID * HID, conv_b1 + l * HID,
            nullptr, nullptr, nullptr, t, sI, N, invN);
        // t = relu(BN_inner(t)) @ W2 + b2, fused outer-BN stats
        gemm_kernel<128, true, true><<<gemmBlocks, 256, 0, stream>>>(
            t, conv_W2 + (long)l * HID * HID, conv_b2 + l * HID,
            sI, conv_g1 + l * HID, conv_bt1 + l * HID, t, sO, N, invN);
        // h = relu(BN_outer(t)); pool into z slices in the same pass
        bn_apply_pool<<<G, 256, 0, stream>>>(
            t, h, sO, bn_g + l * HID, bn_b + l * HID, starts, z, l, invN);
    }

    head_gemm1<<<G, 128, 0, stream>>>(z, head_W1, head_b1, zr);
    head_stats<<<1, 128, 0, stream>>>(zr, ms, G);
    head_final<<<G, 128, 0, stream>>>(zr, ms, head_g, head_bt, head_W2, head_b2, (float*)d_out);
}

// Round 6
// 1226.772 us; speedup vs baseline: 1.6021x; 1.0241x over previous
//
#include <hip/hip_runtime.h>
#include <hip/hip_bf16.h>

#define HID 128
#define EDIM 16

typedef float v4f __attribute__((ext_vector_type(4)));

// ================= CSR build =================
__global__ void hist_kernel(const int* __restrict__ dst, int* __restrict__ deg, int E)
{
    int e = blockIdx.x * 256 + threadIdx.x;
    if (e < E) atomicAdd(&deg[dst[e]], 1);
}

__global__ void block_sum_kernel(const int* __restrict__ deg, int* __restrict__ bsum, int Nn)
{
    int i = blockIdx.x * 256 + threadIdx.x;
    int v = (i < Nn) ? deg[i] : 0;
#pragma unroll
    for (int off = 32; off > 0; off >>= 1) v += __shfl_down(v, off, 64);
    __shared__ int ws[4];
    if ((threadIdx.x & 63) == 0) ws[threadIdx.x >> 6] = v;
    __syncthreads();
    if (threadIdx.x == 0) bsum[blockIdx.x] = ws[0] + ws[1] + ws[2] + ws[3];
}

__global__ void bsum_scan_kernel(int* bsum, int nb, int* total_out)
{
    __shared__ int sh[256];
    int tid = threadIdx.x;
    int v = (tid < nb) ? bsum[tid] : 0;
    sh[tid] = v;
    __syncthreads();
    for (int off = 1; off < 256; off <<= 1) {
        int tv = (tid >= off) ? sh[tid - off] : 0;
        __syncthreads();
        sh[tid] += tv;
        __syncthreads();
    }
    if (tid < nb) bsum[tid] = sh[tid] - v;
    if (tid == 255) *total_out = sh[255];
}

__global__ void block_scan_kernel(const int* __restrict__ deg, const int* __restrict__ bsum,
                                  int* __restrict__ row_start, int* __restrict__ cursor, int Nn)
{
    __shared__ int sh[256];
    int tid = threadIdx.x;
    int i = blockIdx.x * 256 + tid;
    int v = (i < Nn) ? deg[i] : 0;
    sh[tid] = v;
    __syncthreads();
    for (int off = 1; off < 256; off <<= 1) {
        int tv = (tid >= off) ? sh[tid - off] : 0;
        __syncthreads();
        sh[tid] += tv;
        __syncthreads();
    }
    if (i < Nn) {
        int excl = sh[tid] - v + bsum[blockIdx.x];
        row_start[i] = excl;
        cursor[i] = excl;
    }
}

__global__ void scatter_kernel(const int* __restrict__ src, const int* __restrict__ dst,
                               int* cursor, int* __restrict__ perm,
                               int* __restrict__ src_perm, int E)
{
    int e = blockIdx.x * 256 + threadIdx.x;
    if (e >= E) return;
    int pos = atomicAdd(&cursor[dst[e]], 1);
    perm[pos] = e;
    src_perm[pos] = src[e];
}

__global__ void gather_ea_kernel(const float* __restrict__ ea, const int* __restrict__ perm,
                                 float* __restrict__ ea_perm, int E)
{
    int idx = blockIdx.x * 256 + threadIdx.x;
    int p = idx >> 2, c = (idx & 3) * 4;
    if (p >= E) return;
    int e = perm[p];
    *(float4*)&ea_perm[(long)p * EDIM + c] = *(const float4*)&ea[(long)e * EDIM + c];
}

// ====== Node-centric aggregation: 1 wave/node, 2 ch/lane, 32-bit addressing ======
__device__ __forceinline__ void matv2(const v4f& a0, const v4f& a1,
                                      const v4f& a2, const v4f& a3,
                                      const float2* __restrict__ w,
                                      float& m0, float& m1)
{
    m0 += a0.x*w[0].x + a0.y*w[1].x + a0.z*w[2].x + a0.w*w[3].x
        + a1.x*w[4].x + a1.y*w[5].x + a1.z*w[6].x + a1.w*w[7].x
        + a2.x*w[8].x + a2.y*w[9].x + a2.z*w[10].x + a2.w*w[11].x
        + a3.x*w[12].x + a3.y*w[13].x + a3.z*w[14].x + a3.w*w[15].x;
    m1 += a0.x*w[0].y + a0.y*w[1].y + a0.z*w[2].y + a0.w*w[3].y
        + a1.x*w[4].y + a1.y*w[5].y + a1.z*w[6].y + a1.w*w[7].y
        + a2.x*w[8].y + a2.y*w[9].y + a2.z*w[10].y + a2.w*w[11].y
        + a3.x*w[12].y + a3.y*w[13].y + a3.z*w[14].y + a3.w*w[15].y;
}

template<bool GATH>
__global__ __launch_bounds__(256, 4) void aggregate_kernel(
    const float* __restrict__ h, const float* __restrict__ eaG,
    const int* __restrict__ perm, const int* __restrict__ src_perm,
    const int* __restrict__ row_start,
    const float* __restrict__ We, const float* __restrict__ be,
    float* __restrict__ t, int Nn)
{
    int tid = threadIdx.x;
    int c = (tid & 63) * 2;                 // channels c, c+1
    float2 w[16];
#pragma unroll
    for (int k = 0; k < 16; ++k) w[k] = *(const float2*)&We[k * HID + c];
    float2 bj = *(const float2*)&be[c];
    int node = blockIdx.x * 4 + (tid >> 6);
    if (node >= Nn) return;
    const float* __restrict__ hc = h + c;   // lane-fixed channel base
    float2 acc = *(const float2*)(hc + ((unsigned)node << 7));
    int p0 = row_start[node], p1 = row_start[node + 1];
    int rem = p1 - p0;
    int p = p0;
    const v4f* ep = (const v4f*)eaG + (size_t)(unsigned)p0 * 4u;  // GATH: running base
    int s0 = 0, s1 = 0, s2 = 0, s3 = 0;
    if (rem >= 4) { s0 = src_perm[p]; s1 = src_perm[p + 1]; s2 = src_perm[p + 2]; s3 = src_perm[p + 3]; }
    while (rem >= 4) {
        int nrem = rem - 4;
        int np = p + 4;
        int t0 = 0, t1 = 0, t2 = 0, t3 = 0;
        if (nrem >= 4) { t0 = src_perm[np]; t1 = src_perm[np + 1]; t2 = src_perm[np + 2]; t3 = src_perm[np + 3]; }
        float2 h0 = *(const float2*)(hc + ((unsigned)s0 << 7));
        float2 h1 = *(const float2*)(hc + ((unsigned)s1 << 7));
        float2 h2 = *(const float2*)(hc + ((unsigned)s2 << 7));
        float2 h3 = *(const float2*)(hc + ((unsigned)s3 << 7));
        v4f a00, a01, a02, a03, a10, a11, a12, a13;
        v4f a20, a21, a22, a23, a30, a31, a32, a33;
        if (GATH) {
            a00 = __builtin_nontemporal_load(ep + 0);
            a01 = __builtin_nontemporal_load(ep + 1);
            a02 = __builtin_nontemporal_load(ep + 2);
            a03 = __builtin_nontemporal_load(ep + 3);
            a10 = __builtin_nontemporal_load(ep + 4);
            a11 = __builtin_nontemporal_load(ep + 5);
            a12 = __builtin_nontemporal_load(ep + 6);
            a13 = __builtin_nontemporal_load(ep + 7);
            a20 = __builtin_nontemporal_load(ep + 8);
            a21 = __builtin_nontemporal_load(ep + 9);
            a22 = __builtin_nontemporal_load(ep + 10);
            a23 = __builtin_nontemporal_load(ep + 11);
            a30 = __builtin_nontemporal_load(ep + 12);
            a31 = __builtin_nontemporal_load(ep + 13);
            a32 = __builtin_nontemporal_load(ep + 14);
            a33 = __builtin_nontemporal_load(ep + 15);
        } else {
            const v4f* e0 = (const v4f*)eaG + (size_t)(unsigned)perm[p] * 4u;
            const v4f* e1 = (const v4f*)eaG + (size_t)(unsigned)perm[p + 1] * 4u;
            const v4f* e2 = (const v4f*)eaG + (size_t)(unsigned)perm[p + 2] * 4u;
            const v4f* e3 = (const v4f*)eaG + (size_t)(unsigned)perm[p + 3] * 4u;
            a00 = e0[0]; a01 = e0[1]; a02 = e0[2]; a03 = e0[3];
            a10 = e1[0]; a11 = e1[1]; a12 = e1[2]; a13 = e1[3];
            a20 = e2[0]; a21 = e2[1]; a22 = e2[2]; a23 = e2[3];
            a30 = e3[0]; a31 = e3[1]; a32 = e3[2]; a33 = e3[3];
        }
        float m00 = bj.x + h0.x, m01 = bj.y + h0.y;
        float m10 = bj.x + h1.x, m11 = bj.y + h1.y;
        float m20 = bj.x + h2.x, m21 = bj.y + h2.y;
        float m30 = bj.x + h3.x, m31 = bj.y + h3.y;
        matv2(a00, a01, a02, a03, w, m00, m01);
        matv2(a10, a11, a12, a13, w, m10, m11);
        matv2(a20, a21, a22, a23, w, m20, m21);
        matv2(a30, a31, a32, a33, w, m30, m31);
        acc.x += fmaxf(m00, 0.f) + fmaxf(m10, 0.f) + fmaxf(m20, 0.f) + fmaxf(m30, 0.f);
        acc.y += fmaxf(m01, 0.f) + fmaxf(m11, 0.f) + fmaxf(m21, 0.f) + fmaxf(m31, 0.f);
        ep += 16;
        p = np; rem = nrem;
        s0 = t0; s1 = t1; s2 = t2; s3 = t3;
    }
    for (; rem > 0; --rem, ++p) {
        int s = src_perm[p];
        const v4f* e0 = GATH ? ((const v4f*)eaG + (size_t)(unsigned)p * 4u)
                             : ((const v4f*)eaG + (size_t)(unsigned)perm[p] * 4u);
        v4f a0 = e0[0], a1 = e0[1], a2 = e0[2], a3 = e0[3];
        float2 hv = *(const float2*)(hc + ((unsigned)s << 7));
        float m0 = bj.x + hv.x, m1 = bj.y + hv.y;
        matv2(a0, a1, a2, a3, w, m0, m1);
        acc.x += fmaxf(m0, 0.f);
        acc.y += fmaxf(m1, 0.f);
    }
    *(float2*)(t + ((unsigned)node << 7) + c) = acc;
}

// ================= GEMM: 128x128 tile, 8x8 per thread, fused pre-BN / post-stats =================
template<int K, bool PRE_BN, bool POST_STATS>
__global__ __launch_bounds__(256) void gemm_kernel(
    const float* __restrict__ A, const float* __restrict__ W, const float* __restrict__ bias,
    const float* __restrict__ preStats, const float* __restrict__ preG, const float* __restrict__ preB,
    float* __restrict__ C, float* __restrict__ postStats, int Nrows, float invN)
{
    __shared__ __align__(16) float At[32 * 132];   // [k][r] transposed, padded
    __shared__ __align__(16) float Wl[32 * 128];   // [k][c]
    __shared__ float sc[PRE_BN ? K : 1], sb[PRE_BN ? K : 1];
    int tid = threadIdx.x;
    int rbase = blockIdx.x * 128;
    if (PRE_BN) {
        if (tid < K) {
            float mean = preStats[tid] * invN;
            float var = preStats[K + tid] * invN - mean * mean;
            float rstd = rsqrtf(var + 1e-5f);
            float g = preG[tid];
            sc[tid] = rstd * g;
            sb[tid] = preB[tid] - mean * rstd * g;
        }
        __syncthreads();
    }
    int tx = tid & 15, ty = tid >> 4;
    int c0 = tx * 8, r0 = ty * 8;
    float acc[8][8];
#pragma unroll
    for (int i = 0; i < 8; ++i)
#pragma unroll
        for (int jj = 0; jj < 8; ++jj) acc[i][jj] = 0.f;

    for (int k0 = 0; k0 < K; k0 += 32) {
#pragma unroll
        for (int i = 0; i < 4; ++i) {
            int idx = tid + i * 256;           // 1024 float4s: 128 rows x 8
            int r = idx >> 3, kk = (idx & 7) * 4;
            int gr = rbase + r;
            float4 v = make_float4(0.f, 0.f, 0.f, 0.f);
            if (gr < Nrows) v = *(const float4*)&A[(long)gr * K + k0 + kk];
            if (PRE_BN) {
                v.x = fmaxf(v.x * sc[k0 + kk]     + sb[k0 + kk],     0.f);
                v.y = fmaxf(v.y * sc[k0 + kk + 1] + sb[k0 + kk + 1], 0.f);
                v.z = fmaxf(v.z * sc[k0 + kk + 2] + sb[k0 + kk + 2], 0.f);
                v.w = fmaxf(v.w * sc[k0 + kk + 3] + sb[k0 + kk + 3], 0.f);
            }
            At[(kk + 0) * 132 + r] = v.x;
            At[(kk + 1) * 132 + r] = v.y;
            At[(kk + 2) * 132 + r] = v.z;
            At[(kk + 3) * 132 + r] = v.w;
        }
#pragma unroll
        for (int i = 0; i < 4; ++i) {
            int idx = tid + i * 256;           // 1024 float4s: 32 k x 32
            int kk = idx >> 5, c4 = (idx & 31) * 4;
            *(float4*)&Wl[kk * 128 + c4] = *(const float4*)&W[(long)(k0 + kk) * HID + c4];
        }
        __syncthreads();
#pragma unroll
        for (int k = 0; k < 32; ++k) {
            float4 a0 = *(const float4*)&At[k * 132 + r0];
            float4 a1 = *(const float4*)&At[k * 132 + r0 + 4];
            float4 w0 = *(const float4*)&Wl[k * 128 + c0];
            float4 w1 = *(const float4*)&Wl[k * 128 + c0 + 4];
            float av[8] = {a0.x, a0.y, a0.z, a0.w, a1.x, a1.y, a1.z, a1.w};
            float wv[8] = {w0.x, w0.y, w0.z, w0.w, w1.x, w1.y, w1.z, w1.w};
#pragma unroll
            for (int i = 0; i < 8; ++i)
#pragma unroll
                for (int jj = 0; jj < 8; ++jj) acc[i][jj] += av[i] * wv[jj];
        }
        __syncthreads();
    }

    float4 bq0 = *(const float4*)&bias[c0];
    float4 bq1 = *(const float4*)&bias[c0 + 4];
    float bv[8] = {bq0.x, bq0.y, bq0.z, bq0.w, bq1.x, bq1.y, bq1.z, bq1.w};
    float s[8], q[8];
#pragma unroll
    for (int jj = 0; jj < 8; ++jj) { s[jj] = 0.f; q[jj] = 0.f; }
#pragma unroll
    for (int i = 0; i < 8; ++i) {
        int gr = rbase + r0 + i;
        if (gr < Nrows) {
            float outv[8];
#pragma unroll
            for (int jj = 0; jj < 8; ++jj) {
                outv[jj] = acc[i][jj] + bv[jj];
                if (POST_STATS) { s[jj] += outv[jj]; q[jj] += outv[jj] * outv[jj]; }
            }
            *(float4*)&C[(long)gr * HID + c0]     = make_float4(outv[0], outv[1], outv[2], outv[3]);
            *(float4*)&C[(long)gr * HID + c0 + 4] = make_float4(outv[4], outv[5], outv[6], outv[7]);
        }
    }
    if (POST_STATS) {
        float* redS = At;   // reuse (k-loop's final barrier already passed)
        float* redQ = Wl;
#pragma unroll
        for (int jj = 0; jj < 8; ++jj) {
            redS[ty * 128 + c0 + jj] = s[jj];
            redQ[ty * 128 + c0 + jj] = q[jj];
        }
        __syncthreads();
        if (tid < 128) {
            float S = 0.f, Q = 0.f;
#pragma unroll
            for (int g2 = 0; g2 < 16; ++g2) { S += redS[g2 * 128 + tid]; Q += redQ[g2 * 128 + tid]; }
            atomicAdd(&postStats[tid], S);
            atomicAdd(&postStats[128 + tid], Q);
        }
    }
}

// ================= fused BN apply + ReLU + per-graph pooling (512 thr: 4 walkers) =================
__global__ void bn_apply_pool(const float* __restrict__ X, float* __restrict__ h,
                              const float* __restrict__ stats, const float* __restrict__ g,
                              const float* __restrict__ b, const int* __restrict__ starts,
                              float* __restrict__ z, int l, float invN)
{
    int gph = blockIdx.x;
    int tid = threadIdx.x;
    int j = tid & 127, q = tid >> 7;   // 4 row-walkers
    float mean = stats[j] * invN;
    float var = stats[128 + j] * invN - mean * mean;
    float rstd = rsqrtf(var + 1e-5f);
    float gg = g[j];
    float scale = rstd * gg;
    float shift = b[j] - mean * rstd * gg;
    int s = starts[gph], e = starts[gph + 1];
    float sum = 0.f, mx = 0.f;                 // outputs >= 0 after ReLU
    for (int n = s + q; n < e; n += 4) {
        float v = fmaxf(X[(long)n * HID + j] * scale + shift, 0.f);
        h[(long)n * HID + j] = v;
        sum += v; mx = fmaxf(mx, v);
    }
    __shared__ float ls[512], lm[512];
    ls[tid] = sum; lm[tid] = mx;
    __syncthreads();
    if (tid < 128) {
        sum = ls[tid] + ls[tid + 128] + ls[tid + 256] + ls[tid + 384];
        mx = fmaxf(fmaxf(lm[tid], lm[tid + 128]), fmaxf(lm[tid + 256], lm[tid + 384]));
        float cnt = (float)(e - s);
        z[(long)gph * 768 + l * 128 + tid] = sum / fmaxf(cnt, 1.f);
        z[(long)gph * 768 + 384 + l * 128 + tid] = mx;
    }
}

// ================= segment boundaries (batch sorted) =================
__global__ void starts_kernel(const int* __restrict__ batch, int* __restrict__ starts,
                              int Nn, int Gn)
{
    int g = blockIdx.x * blockDim.x + threadIdx.x;
    if (g > Gn) return;
    int lo = 0, hi = Nn;
    while (lo < hi) { int mid = (lo + hi) >> 1; if (batch[mid] < g) lo = mid + 1; else hi = mid; }
    starts[g] = lo;
}

// ================= head =================
__global__ void head_gemm1(const float* __restrict__ z, const float* __restrict__ W,
                           const float* __restrict__ bias, float* __restrict__ zr)
{
    __shared__ __align__(16) float zl[768];
    int g = blockIdx.x, j = threadIdx.x;
    for (int i = j; i < 768; i += 128) zl[i] = z[(long)g * 768 + i];
    __syncthreads();
    float acc = bias[j];
    for (int k = 0; k < 768; k += 4) {
        float4 a4 = *(const float4*)&zl[k];
        acc += a4.x * W[k * 128 + j] + a4.y * W[(k + 1) * 128 + j]
             + a4.z * W[(k + 2) * 128 + j] + a4.w * W[(k + 3) * 128 + j];
    }
    zr[(long)g * 128 + j] = acc;
}

__global__ void head_stats(const float* __restrict__ zr, float* __restrict__ ms, int Gn)
{
    int j = threadIdx.x;  // 128 threads
    float sum = 0.f, sq = 0.f;
    for (int r = 0; r < Gn; ++r) { float v = zr[(long)r * 128 + j]; sum += v; sq += v * v; }
    float mean = sum / (float)Gn;
    float var = sq / (float)Gn - mean * mean;
    ms[j] = mean;
    ms[128 + j] = rsqrtf(var + 1e-5f);
}

__global__ void head_final(const float* __restrict__ zr, const float* __restrict__ ms,
                           const float* __restrict__ hg, const float* __restrict__ hb,
                           const float* __restrict__ W2, const float* __restrict__ b2,
                           float* __restrict__ out)
{
    int g = blockIdx.x, j = threadIdx.x;
    float v = zr[(long)g * 128 + j];
    v = (v - ms[j]) * ms[128 + j] * hg[j] + hb[j];
    v = fmaxf(v, 0.f);
    float p = v * W2[j];
#pragma unroll
    for (int off = 32; off > 0; off >>= 1) p += __shfl_down(p, off, 64);
    __shared__ float partial[2];
    if ((j & 63) == 0) partial[j >> 6] = p;
    __syncthreads();
    if (j == 0) out[g] = partial[0] + partial[1] + b2[0];
}

extern "C" void kernel_launch(void* const* d_in, const int* in_sizes, int n_in,
                              void* d_out, int out_size, void* d_ws, size_t ws_size,
                              hipStream_t stream)
{
    const float* x         = (const float*)d_in[0];
    const float* edge_attr = (const float*)d_in[1];
    const int*   src       = (const int*)d_in[2];
    const int*   dst       = (const int*)d_in[3];
    const int*   batch     = (const int*)d_in[4];
    const float* Wp        = (const float*)d_in[5];
    const float* bp        = (const float*)d_in[6];
    const float* conv_We   = (const float*)d_in[7];
    const float* conv_be   = (const float*)d_in[8];
    const float* conv_W1   = (const float*)d_in[9];
    const float* conv_b1   = (const float*)d_in[10];
    const float* conv_g1   = (const float*)d_in[11];
    const float* conv_bt1  = (const float*)d_in[12];
    const float* conv_W2   = (const float*)d_in[13];
    const float* conv_b2   = (const float*)d_in[14];
    const float* bn_g      = (const float*)d_in[15];
    const float* bn_b      = (const float*)d_in[16];
    const float* head_W1   = (const float*)d_in[17];
    const float* head_b1   = (const float*)d_in[18];
    const float* head_g    = (const float*)d_in[19];
    const float* head_bt   = (const float*)d_in[20];
    const float* head_W2   = (const float*)d_in[21];
    const float* head_b2   = (const float*)d_in[22];

    const int N = in_sizes[4];            // 50000
    const int E = in_sizes[2];            // 800000
    const int G = out_size;               // 256
    const int L = 3;

    // ---- workspace layout ----
    float* h        = (float*)d_ws;                  // N*128
    float* t        = h + (long)N * HID;             // N*128
    float* z        = t + (long)N * HID;             // G*768
    float* zr       = z + (long)G * 768;             // G*128
    float* statsAll = zr + (long)G * HID;            // 7*256
    int*   starts   = (int*)(statsAll + 7 * 256);    // G+1
    int*   row_start= starts + (G + 1);              // N+1
    int*   cursor   = row_start + (N + 1);           // N
    int*   deg      = cursor + N;                    // N
    int*   bsum     = deg + N;                       // 256
    int*   perm     = bsum + 256;                    // E
    int*   src_perm = perm + E;                      // E
    size_t base_end = (size_t)((char*)(src_perm + E) - (char*)d_ws);
    size_t ea_off = (base_end + 15) & ~(size_t)15;
    bool gath = (ea_off + (size_t)E * EDIM * sizeof(float)) <= ws_size;
    float* ea_perm = (float*)((char*)d_ws + ea_off);
    float* ms = statsAll + 6 * 256;

    (void)n_in;

    const float invN = 1.0f / (float)N;
    const int nb = (N + 255) / 256;
    const int gemmBlocks = (N + 127) / 128;

    // ---- CSR build ----
    (void)hipMemsetAsync(deg, 0, (size_t)N * sizeof(int), stream);
    hist_kernel<<<(E + 255) / 256, 256, 0, stream>>>(dst, deg, E);
    block_sum_kernel<<<nb, 256, 0, stream>>>(deg, bsum, N);
    bsum_scan_kernel<<<1, 256, 0, stream>>>(bsum, nb, &row_start[N]);
    block_scan_kernel<<<nb, 256, 0, stream>>>(deg, bsum, row_start, cursor, N);
    scatter_kernel<<<(E + 255) / 256, 256, 0, stream>>>(src, dst, cursor, perm, src_perm, E);
    if (gath)
        gather_ea_kernel<<<(E * 4 + 255) / 256, 256, 0, stream>>>(edge_attr, perm, ea_perm, E);
    starts_kernel<<<1, 512, 0, stream>>>(batch, starts, N, G);
    (void)hipMemsetAsync(statsAll, 0, 7 * 256 * sizeof(float), stream);

    // h = x @ Wp + bp
    gemm_kernel<64, false, false><<<gemmBlocks, 256, 0, stream>>>(
        x, Wp, bp, nullptr, nullptr, nullptr, h, nullptr, N, invN);

    for (int l = 0; l < L; ++l) {
        float* sI = statsAll + l * 512;
        float* sO = sI + 256;
        if (gath)
            aggregate_kernel<true><<<(N + 3) / 4, 256, 0, stream>>>(
                h, ea_perm, perm, src_perm, row_start,
                conv_We + (long)l * EDIM * HID, conv_be + l * HID, t, N);
        else
            aggregate_kernel<false><<<(N + 3) / 4, 256, 0, stream>>>(
                h, edge_attr, perm, src_perm, row_start,
                conv_We + (long)l * EDIM * HID, conv_be + l * HID, t, N);
        // t = t @ W1 + b1, fused inner-BN stats
        gemm_kernel<128, false, true><<<gemmBlocks, 256, 0, stream>>>(
            t, conv_W1 + (long)l * HID * HID, conv_b1 + l * HID,
            nullptr, nullptr, nullptr, t, sI, N, invN);
        // t = relu(BN_inner(t)) @ W2 + b2, fused outer-BN stats
        gemm_kernel<128, true, true><<<gemmBlocks, 256, 0, stream>>>(
            t, conv_W2 + (long)l * HID * HID, conv_b2 + l * HID,
            sI, conv_g1 + l * HID, conv_bt1 + l * HID, t, sO, N, invN);
        // h = relu(BN_outer(t)); pool into z slices in the same pass
        bn_apply_pool<<<G, 512, 0, stream>>>(
            t, h, sO, bn_g + l * HID, bn_b + l * HID, starts, z, l, invN);
    }

    head_gemm1<<<G, 128, 0, stream>>>(z, head_W1, head_b1, zr);
    head_stats<<<1, 128, 0, stream>>>(zr, ms, G);
    head_final<<<G, 128, 0, stream>>>(zr, ms, head_g, head_bt, head_W2, head_b2, (float*)d_out);
}

// Round 7
// 868.341 us; speedup vs baseline: 2.2634x; 1.4128x over previous
//
#include <hip/hip_runtime.h>
#include <hip/hip_bf16.h>

#define HID 128
#define EDIM 16

typedef float v4f __attribute__((ext_vector_type(4)));

// ================= CSR build =================
__global__ void hist_kernel(const int* __restrict__ dst, int* __restrict__ deg, int E)
{
    int e = blockIdx.x * 256 + threadIdx.x;
    if (e < E) atomicAdd(&deg[dst[e]], 1);
}

__global__ void block_sum_kernel(const int* __restrict__ deg, int* __restrict__ bsum, int Nn)
{
    int i = blockIdx.x * 256 + threadIdx.x;
    int v = (i < Nn) ? deg[i] : 0;
#pragma unroll
    for (int off = 32; off > 0; off >>= 1) v += __shfl_down(v, off, 64);
    __shared__ int ws[4];
    if ((threadIdx.x & 63) == 0) ws[threadIdx.x >> 6] = v;
    __syncthreads();
    if (threadIdx.x == 0) bsum[blockIdx.x] = ws[0] + ws[1] + ws[2] + ws[3];
}

__global__ void bsum_scan_kernel(int* bsum, int nb, int* total_out)
{
    __shared__ int sh[256];
    int tid = threadIdx.x;
    int v = (tid < nb) ? bsum[tid] : 0;
    sh[tid] = v;
    __syncthreads();
    for (int off = 1; off < 256; off <<= 1) {
        int tv = (tid >= off) ? sh[tid - off] : 0;
        __syncthreads();
        sh[tid] += tv;
        __syncthreads();
    }
    if (tid < nb) bsum[tid] = sh[tid] - v;
    if (tid == 255) *total_out = sh[255];
}

__global__ void block_scan_kernel(const int* __restrict__ deg, const int* __restrict__ bsum,
                                  int* __restrict__ row_start, int* __restrict__ cursor, int Nn)
{
    __shared__ int sh[256];
    int tid = threadIdx.x;
    int i = blockIdx.x * 256 + tid;
    int v = (i < Nn) ? deg[i] : 0;
    sh[tid] = v;
    __syncthreads();
    for (int off = 1; off < 256; off <<= 1) {
        int tv = (tid >= off) ? sh[tid - off] : 0;
        __syncthreads();
        sh[tid] += tv;
        __syncthreads();
    }
    if (i < Nn) {
        int excl = sh[tid] - v + bsum[blockIdx.x];
        row_start[i] = excl;
        cursor[i] = excl;
    }
}

__global__ void scatter_kernel(const int* __restrict__ src, const int* __restrict__ dst,
                               int* cursor, int* __restrict__ perm,
                               int* __restrict__ src_perm, int E)
{
    int e = blockIdx.x * 256 + threadIdx.x;
    if (e >= E) return;
    int pos = atomicAdd(&cursor[dst[e]], 1);
    perm[pos] = e;
    src_perm[pos] = src[e];
}

__global__ void gather_ea_kernel(const float* __restrict__ ea, const int* __restrict__ perm,
                                 float* __restrict__ ea_perm, int E)
{
    int idx = blockIdx.x * 256 + threadIdx.x;
    int p = idx >> 2, c = (idx & 3) * 4;
    if (p >= E) return;
    int e = perm[p];
    *(float4*)&ea_perm[(long)p * EDIM + c] = *(const float4*)&ea[(long)e * EDIM + c];
}

// ====== Node-centric aggregation: 1 wave/node, 2 ch/lane ======
// Wave-uniform edge addresses are routed through the SCALAR pipe (readfirstlane
// -> s_load), so the vector-memory path carries only the lane-varying h gather.
__device__ __forceinline__ void matv2(const v4f& a0, const v4f& a1,
                                      const v4f& a2, const v4f& a3,
                                      const float2* __restrict__ w,
                                      float& m0, float& m1)
{
    m0 += a0.x*w[0].x + a0.y*w[1].x + a0.z*w[2].x + a0.w*w[3].x
        + a1.x*w[4].x + a1.y*w[5].x + a1.z*w[6].x + a1.w*w[7].x
        + a2.x*w[8].x + a2.y*w[9].x + a2.z*w[10].x + a2.w*w[11].x
        + a3.x*w[12].x + a3.y*w[13].x + a3.z*w[14].x + a3.w*w[15].x;
    m1 += a0.x*w[0].y + a0.y*w[1].y + a0.z*w[2].y + a0.w*w[3].y
        + a1.x*w[4].y + a1.y*w[5].y + a1.z*w[6].y + a1.w*w[7].y
        + a2.x*w[8].y + a2.y*w[9].y + a2.z*w[10].y + a2.w*w[11].y
        + a3.x*w[12].y + a3.y*w[13].y + a3.z*w[14].y + a3.w*w[15].y;
}

template<bool GATH>
__global__ __launch_bounds__(256, 6) void aggregate_kernel(
    const float* __restrict__ h, const float* __restrict__ eaG,
    const int* __restrict__ perm, const int* __restrict__ src_perm,
    const int* __restrict__ row_start,
    const float* __restrict__ We, const float* __restrict__ be,
    float* __restrict__ t, int Nn)
{
    int tid = threadIdx.x;
    int c = (tid & 63) * 2;                 // channels c, c+1
    float2 w[16];
#pragma unroll
    for (int k = 0; k < 16; ++k) w[k] = *(const float2*)&We[k * HID + c];
    float2 bj = *(const float2*)&be[c];
    int node = blockIdx.x * 4 + (tid >> 6);
    if (node >= Nn) return;
    const float* __restrict__ hc = h + c;   // lane-fixed channel base
    float2 acc = *(const float2*)(hc + ((unsigned)node << 7));
    // wave-uniform scalars -> SGPRs
    int p0 = __builtin_amdgcn_readfirstlane(row_start[node]);
    int p1 = __builtin_amdgcn_readfirstlane(row_start[node + 1]);
    int p = p0;
    int s0 = 0, s1 = 0, s2 = 0, s3 = 0;
    if (p + 4 <= p1) { s0 = src_perm[p]; s1 = src_perm[p + 1]; s2 = src_perm[p + 2]; s3 = src_perm[p + 3]; }
    while (p + 4 <= p1) {
        int np = p + 4;
        int t0 = 0, t1 = 0, t2 = 0, t3 = 0;
        if (np + 4 <= p1) { t0 = src_perm[np]; t1 = src_perm[np + 1]; t2 = src_perm[np + 2]; t3 = src_perm[np + 3]; }
        // lane-varying h gather (the only vector-memory traffic in the loop)
        float2 h0 = *(const float2*)(hc + ((unsigned)s0 << 7));
        float2 h1 = *(const float2*)(hc + ((unsigned)s1 << 7));
        float2 h2 = *(const float2*)(hc + ((unsigned)s2 << 7));
        float2 h3 = *(const float2*)(hc + ((unsigned)s3 << 7));
        // wave-uniform ea rows: scalar loads
        int q0, q1, q2, q3;
        if (GATH) { q0 = p; q1 = p + 1; q2 = p + 2; q3 = p + 3; }
        else      { q0 = perm[p]; q1 = perm[p + 1]; q2 = perm[p + 2]; q3 = perm[p + 3]; }
        const v4f* e0 = (const v4f*)(eaG + (size_t)(unsigned)q0 * EDIM);
        const v4f* e1 = (const v4f*)(eaG + (size_t)(unsigned)q1 * EDIM);
        const v4f* e2 = (const v4f*)(eaG + (size_t)(unsigned)q2 * EDIM);
        const v4f* e3 = (const v4f*)(eaG + (size_t)(unsigned)q3 * EDIM);
        v4f a00 = e0[0], a01 = e0[1], a02 = e0[2], a03 = e0[3];
        v4f a10 = e1[0], a11 = e1[1], a12 = e1[2], a13 = e1[3];
        v4f a20 = e2[0], a21 = e2[1], a22 = e2[2], a23 = e2[3];
        v4f a30 = e3[0], a31 = e3[1], a32 = e3[2], a33 = e3[3];
        float m00 = bj.x + h0.x, m01 = bj.y + h0.y;
        float m10 = bj.x + h1.x, m11 = bj.y + h1.y;
        float m20 = bj.x + h2.x, m21 = bj.y + h2.y;
        float m30 = bj.x + h3.x, m31 = bj.y + h3.y;
        matv2(a00, a01, a02, a03, w, m00, m01);
        matv2(a10, a11, a12, a13, w, m10, m11);
        matv2(a20, a21, a22, a23, w, m20, m21);
        matv2(a30, a31, a32, a33, w, m30, m31);
        acc.x += fmaxf(m00, 0.f) + fmaxf(m10, 0.f) + fmaxf(m20, 0.f) + fmaxf(m30, 0.f);
        acc.y += fmaxf(m01, 0.f) + fmaxf(m11, 0.f) + fmaxf(m21, 0.f) + fmaxf(m31, 0.f);
        p = np;
        s0 = t0; s1 = t1; s2 = t2; s3 = t3;
    }
    for (; p < p1; ++p) {
        int s = src_perm[p];
        int q = GATH ? p : perm[p];
        const v4f* e0 = (const v4f*)(eaG + (size_t)(unsigned)q * EDIM);
        v4f a0 = e0[0], a1 = e0[1], a2 = e0[2], a3 = e0[3];
        float2 hv = *(const float2*)(hc + ((unsigned)s << 7));
        float m0 = bj.x + hv.x, m1 = bj.y + hv.y;
        matv2(a0, a1, a2, a3, w, m0, m1);
        acc.x += fmaxf(m0, 0.f);
        acc.y += fmaxf(m1, 0.f);
    }
    *(float2*)(t + ((unsigned)node << 7) + c) = acc;
}

// ================= GEMM: 128x128 tile, 8x8 per thread, fused pre-BN / post-stats =================
template<int K, bool PRE_BN, bool POST_STATS>
__global__ __launch_bounds__(256) void gemm_kernel(
    const float* __restrict__ A, const float* __restrict__ W, const float* __restrict__ bias,
    const float* __restrict__ preStats, const float* __restrict__ preG, const float* __restrict__ preB,
    float* __restrict__ C, float* __restrict__ postStats, int Nrows, float invN)
{
    __shared__ __align__(16) float At[32 * 132];   // [k][r] transposed, padded
    __shared__ __align__(16) float Wl[32 * 128];   // [k][c]
    __shared__ float sc[PRE_BN ? K : 1], sb[PRE_BN ? K : 1];
    int tid = threadIdx.x;
    int rbase = blockIdx.x * 128;
    if (PRE_BN) {
        if (tid < K) {
            float mean = preStats[tid] * invN;
            float var = preStats[K + tid] * invN - mean * mean;
            float rstd = rsqrtf(var + 1e-5f);
            float g = preG[tid];
            sc[tid] = rstd * g;
            sb[tid] = preB[tid] - mean * rstd * g;
        }
        __syncthreads();
    }
    int tx = tid & 15, ty = tid >> 4;
    int c0 = tx * 8, r0 = ty * 8;
    float acc[8][8];
#pragma unroll
    for (int i = 0; i < 8; ++i)
#pragma unroll
        for (int jj = 0; jj < 8; ++jj) acc[i][jj] = 0.f;

    for (int k0 = 0; k0 < K; k0 += 32) {
#pragma unroll
        for (int i = 0; i < 4; ++i) {
            int idx = tid + i * 256;           // 1024 float4s: 128 rows x 8
            int r = idx >> 3, kk = (idx & 7) * 4;
            int gr = rbase + r;
            float4 v = make_float4(0.f, 0.f, 0.f, 0.f);
            if (gr < Nrows) v = *(const float4*)&A[(long)gr * K + k0 + kk];
            if (PRE_BN) {
                v.x = fmaxf(v.x * sc[k0 + kk]     + sb[k0 + kk],     0.f);
                v.y = fmaxf(v.y * sc[k0 + kk + 1] + sb[k0 + kk + 1], 0.f);
                v.z = fmaxf(v.z * sc[k0 + kk + 2] + sb[k0 + kk + 2], 0.f);
                v.w = fmaxf(v.w * sc[k0 + kk + 3] + sb[k0 + kk + 3], 0.f);
            }
            At[(kk + 0) * 132 + r] = v.x;
            At[(kk + 1) * 132 + r] = v.y;
            At[(kk + 2) * 132 + r] = v.z;
            At[(kk + 3) * 132 + r] = v.w;
        }
#pragma unroll
        for (int i = 0; i < 4; ++i) {
            int idx = tid + i * 256;           // 1024 float4s: 32 k x 32
            int kk = idx >> 5, c4 = (idx & 31) * 4;
            *(float4*)&Wl[kk * 128 + c4] = *(const float4*)&W[(long)(k0 + kk) * HID + c4];
        }
        __syncthreads();
#pragma unroll
        for (int k = 0; k < 32; ++k) {
            float4 a0 = *(const float4*)&At[k * 132 + r0];
            float4 a1 = *(const float4*)&At[k * 132 + r0 + 4];
            float4 w0 = *(const float4*)&Wl[k * 128 + c0];
            float4 w1 = *(const float4*)&Wl[k * 128 + c0 + 4];
            float av[8] = {a0.x, a0.y, a0.z, a0.w, a1.x, a1.y, a1.z, a1.w};
            float wv[8] = {w0.x, w0.y, w0.z, w0.w, w1.x, w1.y, w1.z, w1.w};
#pragma unroll
            for (int i = 0; i < 8; ++i)
#pragma unroll
                for (int jj = 0; jj < 8; ++jj) acc[i][jj] += av[i] * wv[jj];
        }
        __syncthreads();
    }

    float4 bq0 = *(const float4*)&bias[c0];
    float4 bq1 = *(const float4*)&bias[c0 + 4];
    float bv[8] = {bq0.x, bq0.y, bq0.z, bq0.w, bq1.x, bq1.y, bq1.z, bq1.w};
    float s[8], q[8];
#pragma unroll
    for (int jj = 0; jj < 8; ++jj) { s[jj] = 0.f; q[jj] = 0.f; }
#pragma unroll
    for (int i = 0; i < 8; ++i) {
        int gr = rbase + r0 + i;
        if (gr < Nrows) {
            float outv[8];
#pragma unroll
            for (int jj = 0; jj < 8; ++jj) {
                outv[jj] = acc[i][jj] + bv[jj];
                if (POST_STATS) { s[jj] += outv[jj]; q[jj] += outv[jj] * outv[jj]; }
            }
            *(float4*)&C[(long)gr * HID + c0]     = make_float4(outv[0], outv[1], outv[2], outv[3]);
            *(float4*)&C[(long)gr * HID + c0 + 4] = make_float4(outv[4], outv[5], outv[6], outv[7]);
        }
    }
    if (POST_STATS) {
        float* redS = At;   // reuse (k-loop's final barrier already passed)
        float* redQ = Wl;
#pragma unroll
        for (int jj = 0; jj < 8; ++jj) {
            redS[ty * 128 + c0 + jj] = s[jj];
            redQ[ty * 128 + c0 + jj] = q[jj];
        }
        __syncthreads();
        if (tid < 128) {
            float S = 0.f, Q = 0.f;
#pragma unroll
            for (int g2 = 0; g2 < 16; ++g2) { S += redS[g2 * 128 + tid]; Q += redQ[g2 * 128 + tid]; }
            atomicAdd(&postStats[tid], S);
            atomicAdd(&postStats[128 + tid], Q);
        }
    }
}

// ================= fused BN apply + ReLU + per-graph pooling (512 thr: 4 walkers) =================
__global__ void bn_apply_pool(const float* __restrict__ X, float* __restrict__ h,
                              const float* __restrict__ stats, const float* __restrict__ g,
                              const float* __restrict__ b, const int* __restrict__ starts,
                              float* __restrict__ z, int l, float invN)
{
    int gph = blockIdx.x;
    int tid = threadIdx.x;
    int j = tid & 127, q = tid >> 7;   // 4 row-walkers
    float mean = stats[j] * invN;
    float var = stats[128 + j] * invN - mean * mean;
    float rstd = rsqrtf(var + 1e-5f);
    float gg = g[j];
    float scale = rstd * gg;
    float shift = b[j] - mean * rstd * gg;
    int s = starts[gph], e = starts[gph + 1];
    float sum = 0.f, mx = 0.f;                 // outputs >= 0 after ReLU
    for (int n = s + q; n < e; n += 4) {
        float v = fmaxf(X[(long)n * HID + j] * scale + shift, 0.f);
        h[(long)n * HID + j] = v;
        sum += v; mx = fmaxf(mx, v);
    }
    __shared__ float ls[512], lm[512];
    ls[tid] = sum; lm[tid] = mx;
    __syncthreads();
    if (tid < 128) {
        sum = ls[tid] + ls[tid + 128] + ls[tid + 256] + ls[tid + 384];
        mx = fmaxf(fmaxf(lm[tid], lm[tid + 128]), fmaxf(lm[tid + 256], lm[tid + 384]));
        float cnt = (float)(e - s);
        z[(long)gph * 768 + l * 128 + tid] = sum / fmaxf(cnt, 1.f);
        z[(long)gph * 768 + 384 + l * 128 + tid] = mx;
    }
}

// ================= segment boundaries (batch sorted) =================
__global__ void starts_kernel(const int* __restrict__ batch, int* __restrict__ starts,
                              int Nn, int Gn)
{
    int g = blockIdx.x * blockDim.x + threadIdx.x;
    if (g > Gn) return;
    int lo = 0, hi = Nn;
    while (lo < hi) { int mid = (lo + hi) >> 1; if (batch[mid] < g) lo = mid + 1; else hi = mid; }
    starts[g] = lo;
}

// ================= head =================
__global__ void head_gemm1(const float* __restrict__ z, const float* __restrict__ W,
                           const float* __restrict__ bias, float* __restrict__ zr)
{
    __shared__ __align__(16) float zl[768];
    int g = blockIdx.x, j = threadIdx.x;
    for (int i = j; i < 768; i += 128) zl[i] = z[(long)g * 768 + i];
    __syncthreads();
    float acc = bias[j];
    for (int k = 0; k < 768; k += 4) {
        float4 a4 = *(const float4*)&zl[k];
        acc += a4.x * W[k * 128 + j] + a4.y * W[(k + 1) * 128 + j]
             + a4.z * W[(k + 2) * 128 + j] + a4.w * W[(k + 3) * 128 + j];
    }
    zr[(long)g * 128 + j] = acc;
}

__global__ void head_stats(const float* __restrict__ zr, float* __restrict__ ms, int Gn)
{
    int j = threadIdx.x;  // 128 threads
    float sum = 0.f, sq = 0.f;
    for (int r = 0; r < Gn; ++r) { float v = zr[(long)r * 128 + j]; sum += v; sq += v * v; }
    float mean = sum / (float)Gn;
    float var = sq / (float)Gn - mean * mean;
    ms[j] = mean;
    ms[128 + j] = rsqrtf(var + 1e-5f);
}

__global__ void head_final(const float* __restrict__ zr, const float* __restrict__ ms,
                           const float* __restrict__ hg, const float* __restrict__ hb,
                           const float* __restrict__ W2, const float* __restrict__ b2,
                           float* __restrict__ out)
{
    int g = blockIdx.x, j = threadIdx.x;
    float v = zr[(long)g * 128 + j];
    v = (v - ms[j]) * ms[128 + j] * hg[j] + hb[j];
    v = fmaxf(v, 0.f);
    float p = v * W2[j];
#pragma unroll
    for (int off = 32; off > 0; off >>= 1) p += __shfl_down(p, off, 64);
    __shared__ float partial[2];
    if ((j & 63) == 0) partial[j >> 6] = p;
    __syncthreads();
    if (j == 0) out[g] = partial[0] + partial[1] + b2[0];
}

extern "C" void kernel_launch(void* const* d_in, const int* in_sizes, int n_in,
                              void* d_out, int out_size, void* d_ws, size_t ws_size,
                              hipStream_t stream)
{
    const float* x         = (const float*)d_in[0];
    const float* edge_attr = (const float*)d_in[1];
    const int*   src       = (const int*)d_in[2];
    const int*   dst       = (const int*)d_in[3];
    const int*   batch     = (const int*)d_in[4];
    const float* Wp        = (const float*)d_in[5];
    const float* bp        = (const float*)d_in[6];
    const float* conv_We   = (const float*)d_in[7];
    const float* conv_be   = (const float*)d_in[8];
    const float* conv_W1   = (const float*)d_in[9];
    const float* conv_b1   = (const float*)d_in[10];
    const float* conv_g1   = (const float*)d_in[11];
    const float* conv_bt1  = (const float*)d_in[12];
    const float* conv_W2   = (const float*)d_in[13];
    const float* conv_b2   = (const float*)d_in[14];
    const float* bn_g      = (const float*)d_in[15];
    const float* bn_b      = (const float*)d_in[16];
    const float* head_W1   = (const float*)d_in[17];
    const float* head_b1   = (const float*)d_in[18];
    const float* head_g    = (const float*)d_in[19];
    const float* head_bt   = (const float*)d_in[20];
    const float* head_W2   = (const float*)d_in[21];
    const float* head_b2   = (const float*)d_in[22];

    const int N = in_sizes[4];            // 50000
    const int E = in_sizes[2];            // 800000
    const int G = out_size;               // 256
    const int L = 3;

    // ---- workspace layout ----
    float* h        = (float*)d_ws;                  // N*128
    float* t        = h + (long)N * HID;             // N*128
    float* z        = t + (long)N * HID;             // G*768
    float* zr       = z + (long)G * 768;             // G*128
    float* statsAll = zr + (long)G * HID;            // 7*256
    int*   starts   = (int*)(statsAll + 7 * 256);    // G+1
    int*   row_start= starts + (G + 1);              // N+1
    int*   cursor   = row_start + (N + 1);           // N
    int*   deg      = cursor + N;                    // N
    int*   bsum     = deg + N;                       // 256
    int*   perm     = bsum + 256;                    // E
    int*   src_perm = perm + E;                      // E
    size_t base_end = (size_t)((char*)(src_perm + E) - (char*)d_ws);
    size_t ea_off = (base_end + 15) & ~(size_t)15;
    bool gath = (ea_off + (size_t)E * EDIM * sizeof(float)) <= ws_size;
    float* ea_perm = (float*)((char*)d_ws + ea_off);
    float* ms = statsAll + 6 * 256;

    (void)n_in;

    const float invN = 1.0f / (float)N;
    const int nb = (N + 255) / 256;
    const int gemmBlocks = (N + 127) / 128;

    // ---- CSR build ----
    (void)hipMemsetAsync(deg, 0, (size_t)N * sizeof(int), stream);
    hist_kernel<<<(E + 255) / 256, 256, 0, stream>>>(dst, deg, E);
    block_sum_kernel<<<nb, 256, 0, stream>>>(deg, bsum, N);
    bsum_scan_kernel<<<1, 256, 0, stream>>>(bsum, nb, &row_start[N]);
    block_scan_kernel<<<nb, 256, 0, stream>>>(deg, bsum, row_start, cursor, N);
    scatter_kernel<<<(E + 255) / 256, 256, 0, stream>>>(src, dst, cursor, perm, src_perm, E);
    if (gath)
        gather_ea_kernel<<<(E * 4 + 255) / 256, 256, 0, stream>>>(edge_attr, perm, ea_perm, E);
    starts_kernel<<<1, 512, 0, stream>>>(batch, starts, N, G);
    (void)hipMemsetAsync(statsAll, 0, 7 * 256 * sizeof(float), stream);

    // h = x @ Wp + bp
    gemm_kernel<64, false, false><<<gemmBlocks, 256, 0, stream>>>(
        x, Wp, bp, nullptr, nullptr, nullptr, h, nullptr, N, invN);

    for (int l = 0; l < L; ++l) {
        float* sI = statsAll + l * 512;
        float* sO = sI + 256;
        if (gath)
            aggregate_kernel<true><<<(N + 3) / 4, 256, 0, stream>>>(
                h, ea_perm, perm, src_perm, row_start,
                conv_We + (long)l * EDIM * HID, conv_be + l * HID, t, N);
        else
            aggregate_kernel<false><<<(N + 3) / 4, 256, 0, stream>>>(
                h, edge_attr, perm, src_perm, row_start,
                conv_We + (long)l * EDIM * HID, conv_be + l * HID, t, N);
        // t = t @ W1 + b1, fused inner-BN stats
        gemm_kernel<128, false, true><<<gemmBlocks, 256, 0, stream>>>(
            t, conv_W1 + (long)l * HID * HID, conv_b1 + l * HID,
            nullptr, nullptr, nullptr, t, sI, N, invN);
        // t = relu(BN_inner(t)) @ W2 + b2, fused outer-BN stats
        gemm_kernel<128, true, true><<<gemmBlocks, 256, 0, stream>>>(
            t, conv_W2 + (long)l * HID * HID, conv_b2 + l * HID,
            sI, conv_g1 + l * HID, conv_bt1 + l * HID, t, sO, N, invN);
        // h = relu(BN_outer(t)); pool into z slices in the same pass
        bn_apply_pool<<<G, 512, 0, stream>>>(
            t, h, sO, bn_g + l * HID, bn_b + l * HID, starts, z, l, invN);
    }

    head_gemm1<<<G, 128, 0, stream>>>(z, head_W1, head_b1, zr);
    head_stats<<<1, 128, 0, stream>>>(zr, ms, G);
    head_final<<<G, 128, 0, stream>>>(zr, ms, head_g, head_bt, head_W2, head_b2, (float*)d_out);
}

// Round 8
// 843.906 us; speedup vs baseline: 2.3289x; 1.0290x over previous
//
#include <hip/hip_runtime.h>
#include <hip/hip_bf16.h>

#define HID 128
#define EDIM 16

typedef float v4f __attribute__((ext_vector_type(4)));
typedef short s8v __attribute__((ext_vector_type(8)));   // 8 bf16 (4 VGPRs) MFMA frag
typedef float f4v __attribute__((ext_vector_type(4)));   // MFMA acc

#define MFMA_BF16(a, b, c) __builtin_amdgcn_mfma_f32_16x16x32_bf16((a), (b), (c), 0, 0, 0)

__device__ __forceinline__ unsigned short bf16_rne(float v)
{
    unsigned u = __builtin_bit_cast(unsigned, v);
    return (unsigned short)((u + 0x7fffu + ((u >> 16) & 1u)) >> 16);
}

__device__ __forceinline__ void split_bf16(float v, unsigned short& h, unsigned short& l)
{
    unsigned u = __builtin_bit_cast(unsigned, v);
    unsigned hu = (u + 0x7fffu + ((u >> 16) & 1u)) >> 16;
    h = (unsigned short)hu;
    float hf = __builtin_bit_cast(float, hu << 16);
    l = bf16_rne(v - hf);
}

// ================= CSR build =================
__global__ void hist_kernel(const int* __restrict__ dst, int* __restrict__ deg, int E)
{
    int e = blockIdx.x * 256 + threadIdx.x;
    if (e < E) atomicAdd(&deg[dst[e]], 1);
}

__global__ void block_sum_kernel(const int* __restrict__ deg, int* __restrict__ bsum, int Nn)
{
    int i = blockIdx.x * 256 + threadIdx.x;
    int v = (i < Nn) ? deg[i] : 0;
#pragma unroll
    for (int off = 32; off > 0; off >>= 1) v += __shfl_down(v, off, 64);
    __shared__ int ws[4];
    if ((threadIdx.x & 63) == 0) ws[threadIdx.x >> 6] = v;
    __syncthreads();
    if (threadIdx.x == 0) bsum[blockIdx.x] = ws[0] + ws[1] + ws[2] + ws[3];
}

__global__ void bsum_scan_kernel(int* bsum, int nb, int* total_out)
{
    __shared__ int sh[256];
    int tid = threadIdx.x;
    int v = (tid < nb) ? bsum[tid] : 0;
    sh[tid] = v;
    __syncthreads();
    for (int off = 1; off < 256; off <<= 1) {
        int tv = (tid >= off) ? sh[tid - off] : 0;
        __syncthreads();
        sh[tid] += tv;
        __syncthreads();
    }
    if (tid < nb) bsum[tid] = sh[tid] - v;
    if (tid == 255) *total_out = sh[255];
}

__global__ void block_scan_kernel(const int* __restrict__ deg, const int* __restrict__ bsum,
                                  int* __restrict__ row_start, int* __restrict__ cursor, int Nn)
{
    __shared__ int sh[256];
    int tid = threadIdx.x;
    int i = blockIdx.x * 256 + tid;
    int v = (i < Nn) ? deg[i] : 0;
    sh[tid] = v;
    __syncthreads();
    for (int off = 1; off < 256; off <<= 1) {
        int tv = (tid >= off) ? sh[tid - off] : 0;
        __syncthreads();
        sh[tid] += tv;
        __syncthreads();
    }
    if (i < Nn) {
        int excl = sh[tid] - v + bsum[blockIdx.x];
        row_start[i] = excl;
        cursor[i] = excl;
    }
}

__global__ void scatter_kernel(const int* __restrict__ src, const int* __restrict__ dst,
                               int* cursor, int* __restrict__ perm,
                               int* __restrict__ src_perm, int E)
{
    int e = blockIdx.x * 256 + threadIdx.x;
    if (e >= E) return;
    int pos = atomicAdd(&cursor[dst[e]], 1);
    perm[pos] = e;
    src_perm[pos] = src[e];
}

__global__ void gather_ea_kernel(const float* __restrict__ ea, const int* __restrict__ perm,
                                 float* __restrict__ ea_perm, int E)
{
    int idx = blockIdx.x * 256 + threadIdx.x;
    int p = idx >> 2, c = (idx & 3) * 4;
    if (p >= E) return;
    int e = perm[p];
    *(float4*)&ea_perm[(long)p * EDIM + c] = *(const float4*)&ea[(long)e * EDIM + c];
}

// ================= weight prep: fp32 [K,128] -> transposed split-bf16 [128,K] hi/lo =================
// layout in out (ushorts): Wp_hi[128*64] @0, Wp_lo @8192,
// then for m2 = 2*l + (isW2): hi @ 16384 + m2*32768, lo @ +16384
__global__ void prep_weights(const float* __restrict__ Wp, const float* __restrict__ W1,
                             const float* __restrict__ W2, unsigned short* __restrict__ out)
{
    int idx = blockIdx.x * 256 + threadIdx.x;
    if (idx < 8192) {
        int n = idx >> 6, k = idx & 63;
        unsigned short h, l;
        split_bf16(Wp[k * 128 + n], h, l);
        out[idx] = h;
        out[8192 + idx] = l;
    } else {
        int j = idx - 8192;
        if (j >= 6 * 16384) return;
        int m2 = j >> 14;
        int r = j & 16383;
        int n = r >> 7, k = r & 127;
        int l = m2 >> 1;
        const float* Wsrc = (m2 & 1) ? (W2 + l * 16384) : (W1 + l * 16384);
        unsigned short h, lo;
        split_bf16(Wsrc[k * 128 + n], h, lo);
        int base = 16384 + m2 * 32768;
        out[base + r] = h;
        out[base + 16384 + r] = lo;
    }
}

// ====== Node-centric aggregation: 1 wave/node, 2 ch/lane, scalar-pipe edge loads ======
__device__ __forceinline__ void matv2(const v4f& a0, const v4f& a1,
                                      const v4f& a2, const v4f& a3,
                                      const float2* __restrict__ w,
                                      float& m0, float& m1)
{
    m0 += a0.x*w[0].x + a0.y*w[1].x + a0.z*w[2].x + a0.w*w[3].x
        + a1.x*w[4].x + a1.y*w[5].x + a1.z*w[6].x + a1.w*w[7].x
        + a2.x*w[8].x + a2.y*w[9].x + a2.z*w[10].x + a2.w*w[11].x
        + a3.x*w[12].x + a3.y*w[13].x + a3.z*w[14].x + a3.w*w[15].x;
    m1 += a0.x*w[0].y + a0.y*w[1].y + a0.z*w[2].y + a0.w*w[3].y
        + a1.x*w[4].y + a1.y*w[5].y + a1.z*w[6].y + a1.w*w[7].y
        + a2.x*w[8].y + a2.y*w[9].y + a2.z*w[10].y + a2.w*w[11].y
        + a3.x*w[12].y + a3.y*w[13].y + a3.z*w[14].y + a3.w*w[15].y;
}

template<bool GATH>
__global__ __launch_bounds__(256, 6) void aggregate_kernel(
    const float* __restrict__ h, const float* __restrict__ eaG,
    const int* __restrict__ perm, const int* __restrict__ src_perm,
    const int* __restrict__ row_start,
    const float* __restrict__ We, const float* __restrict__ be,
    float* __restrict__ t, int Nn)
{
    int tid = threadIdx.x;
    int c = (tid & 63) * 2;
    float2 w[16];
#pragma unroll
    for (int k = 0; k < 16; ++k) w[k] = *(const float2*)&We[k * HID + c];
    float2 bj = *(const float2*)&be[c];
    int node = blockIdx.x * 4 + (tid >> 6);
    if (node >= Nn) return;
    const float* __restrict__ hc = h + c;
    float2 acc = *(const float2*)(hc + ((unsigned)node << 7));
    int p0 = __builtin_amdgcn_readfirstlane(row_start[node]);
    int p1 = __builtin_amdgcn_readfirstlane(row_start[node + 1]);
    int p = p0;
    int s0 = 0, s1 = 0, s2 = 0, s3 = 0;
    if (p + 4 <= p1) { s0 = src_perm[p]; s1 = src_perm[p + 1]; s2 = src_perm[p + 2]; s3 = src_perm[p + 3]; }
    while (p + 4 <= p1) {
        int np = p + 4;
        int t0 = 0, t1 = 0, t2 = 0, t3 = 0;
        if (np + 4 <= p1) { t0 = src_perm[np]; t1 = src_perm[np + 1]; t2 = src_perm[np + 2]; t3 = src_perm[np + 3]; }
        float2 h0 = *(const float2*)(hc + ((unsigned)s0 << 7));
        float2 h1 = *(const float2*)(hc + ((unsigned)s1 << 7));
        float2 h2 = *(const float2*)(hc + ((unsigned)s2 << 7));
        float2 h3 = *(const float2*)(hc + ((unsigned)s3 << 7));
        int q0, q1, q2, q3;
        if (GATH) { q0 = p; q1 = p + 1; q2 = p + 2; q3 = p + 3; }
        else      { q0 = perm[p]; q1 = perm[p + 1]; q2 = perm[p + 2]; q3 = perm[p + 3]; }
        const v4f* e0 = (const v4f*)(eaG + (size_t)(unsigned)q0 * EDIM);
        const v4f* e1 = (const v4f*)(eaG + (size_t)(unsigned)q1 * EDIM);
        const v4f* e2 = (const v4f*)(eaG + (size_t)(unsigned)q2 * EDIM);
        const v4f* e3 = (const v4f*)(eaG + (size_t)(unsigned)q3 * EDIM);
        v4f a00 = e0[0], a01 = e0[1], a02 = e0[2], a03 = e0[3];
        v4f a10 = e1[0], a11 = e1[1], a12 = e1[2], a13 = e1[3];
        v4f a20 = e2[0], a21 = e2[1], a22 = e2[2], a23 = e2[3];
        v4f a30 = e3[0], a31 = e3[1], a32 = e3[2], a33 = e3[3];
        float m00 = bj.x + h0.x, m01 = bj.y + h0.y;
        float m10 = bj.x + h1.x, m11 = bj.y + h1.y;
        float m20 = bj.x + h2.x, m21 = bj.y + h2.y;
        float m30 = bj.x + h3.x, m31 = bj.y + h3.y;
        matv2(a00, a01, a02, a03, w, m00, m01);
        matv2(a10, a11, a12, a13, w, m10, m11);
        matv2(a20, a21, a22, a23, w, m20, m21);
        matv2(a30, a31, a32, a33, w, m30, m31);
        acc.x += fmaxf(m00, 0.f) + fmaxf(m10, 0.f) + fmaxf(m20, 0.f) + fmaxf(m30, 0.f);
        acc.y += fmaxf(m01, 0.f) + fmaxf(m11, 0.f) + fmaxf(m21, 0.f) + fmaxf(m31, 0.f);
        p = np;
        s0 = t0; s1 = t1; s2 = t2; s3 = t3;
    }
    for (; p < p1; ++p) {
        int s = src_perm[p];
        int q = GATH ? p : perm[p];
        const v4f* e0 = (const v4f*)(eaG + (size_t)(unsigned)q * EDIM);
        v4f a0 = e0[0], a1 = e0[1], a2 = e0[2], a3 = e0[3];
        float2 hv = *(const float2*)(hc + ((unsigned)s << 7));
        float m0 = bj.x + hv.x, m1 = bj.y + hv.y;
        matv2(a0, a1, a2, a3, w, m0, m1);
        acc.x += fmaxf(m0, 0.f);
        acc.y += fmaxf(m1, 0.f);
    }
    *(float2*)(t + ((unsigned)node << 7) + c) = acc;
}

// ================= split-bf16 MFMA GEMM: C[N,128] = f(A[N,K]) @ W[K,128] + bias =================
// A decomposed as Ah+Al (bf16); W pre-decomposed/transposed (Wt[128 n][K k] hi/lo).
// C = Ah*Bh + Ah*Bl + Al*Bh (fp32 acc); relative error ~2^-17.
// Block: 128 rows x 128 cols, 256 thr = 4 waves; wave w owns rows [w*32, w*32+32).
// Frag layouts (mfma_f32_16x16x32_bf16): A[m=lane&15][k=quad*8+j]; B[k=quad*8+j][n=lane&15];
// D col=lane&15, row=quad*4+reg.
#define LPAD 40   // LDS row stride in ushorts (padded from 32)

template<int K, bool PRE_BN, bool POST_STATS>
__global__ __launch_bounds__(256) void gemm_mfma(
    const float* __restrict__ A, const unsigned short* __restrict__ Wh,
    const unsigned short* __restrict__ Wl, const float* __restrict__ bias,
    const float* __restrict__ preStats, const float* __restrict__ preG, const float* __restrict__ preB,
    float* __restrict__ C, float* __restrict__ postStats, int Nrows, float invN)
{
    __shared__ __align__(16) unsigned short Ah[128 * LPAD], Al[128 * LPAD];
    __shared__ __align__(16) unsigned short Bh[128 * LPAD], Bl[128 * LPAD];
    __shared__ float sc[PRE_BN ? K : 1], sb[PRE_BN ? K : 1];
    int tid = threadIdx.x;
    int rbase = blockIdx.x * 128;
    if (PRE_BN) {
        if (tid < K) {
            float mean = preStats[tid] * invN;
            float var = preStats[K + tid] * invN - mean * mean;
            float rstd = rsqrtf(var + 1e-5f);
            float g = preG[tid];
            sc[tid] = rstd * g;
            sb[tid] = preB[tid] - mean * rstd * g;
        }
        __syncthreads();
    }
    int w = tid >> 6, nl = tid & 15, q = (tid >> 4) & 3;
    f4v acc[2][8];
#pragma unroll
    for (int mt = 0; mt < 2; ++mt)
#pragma unroll
        for (int nt = 0; nt < 8; ++nt)
#pragma unroll
            for (int r = 0; r < 4; ++r) acc[mt][nt][r] = 0.f;

    for (int ks = 0; ks < K / 32; ++ks) {
        int k0 = ks * 32;
        if (ks) __syncthreads();   // all reads of previous slice done
        // stage A slice [128 m][32 k]: fp32 -> (preBN) -> split bf16
#pragma unroll
        for (int i = 0; i < 4; ++i) {
            int cidx = tid + i * 256;            // 1024 chunks of 4 floats
            int m = cidx >> 3, k4 = (cidx & 7) * 4;
            int gr = rbase + m;
            float4 v = make_float4(0.f, 0.f, 0.f, 0.f);
            if (gr < Nrows) v = *(const float4*)&A[(size_t)gr * K + k0 + k4];
            if (PRE_BN) {
                v.x = fmaxf(v.x * sc[k0 + k4]     + sb[k0 + k4],     0.f);
                v.y = fmaxf(v.y * sc[k0 + k4 + 1] + sb[k0 + k4 + 1], 0.f);
                v.z = fmaxf(v.z * sc[k0 + k4 + 2] + sb[k0 + k4 + 2], 0.f);
                v.w = fmaxf(v.w * sc[k0 + k4 + 3] + sb[k0 + k4 + 3], 0.f);
            }
            unsigned short h0, l0, h1, l1, h2, l2, h3, l3;
            split_bf16(v.x, h0, l0); split_bf16(v.y, h1, l1);
            split_bf16(v.z, h2, l2); split_bf16(v.w, h3, l3);
            uint2 hp, lp;
            hp.x = (unsigned)h0 | ((unsigned)h1 << 16); hp.y = (unsigned)h2 | ((unsigned)h3 << 16);
            lp.x = (unsigned)l0 | ((unsigned)l1 << 16); lp.y = (unsigned)l2 | ((unsigned)l3 << 16);
            *(uint2*)&Ah[m * LPAD + k4] = hp;
            *(uint2*)&Al[m * LPAD + k4] = lp;
        }
        // stage B slice: Wt[128 n][k0..k0+32) hi/lo (already bf16) -> LDS
#pragma unroll
        for (int i = 0; i < 2; ++i) {
            int g = tid + i * 256;               // 512 groups of 8 ushorts
            int n = g >> 2, kq = (g & 3) * 8;
            uint4 hv = *(const uint4*)&Wh[(size_t)n * K + k0 + kq];
            uint4 lv = *(const uint4*)&Wl[(size_t)n * K + k0 + kq];
            *(uint4*)&Bh[n * LPAD + kq] = hv;
            *(uint4*)&Bl[n * LPAD + kq] = lv;
        }
        __syncthreads();
        // A frags for this wave's 2 m-tiles
        s8v ah0 = *(const s8v*)&Ah[(w * 32 + nl) * LPAD + q * 8];
        s8v ah1 = *(const s8v*)&Ah[(w * 32 + 16 + nl) * LPAD + q * 8];
        s8v al0 = *(const s8v*)&Al[(w * 32 + nl) * LPAD + q * 8];
        s8v al1 = *(const s8v*)&Al[(w * 32 + 16 + nl) * LPAD + q * 8];
#pragma unroll
        for (int nt = 0; nt < 8; ++nt) {
            s8v bh = *(const s8v*)&Bh[(nt * 16 + nl) * LPAD + q * 8];
            s8v bl = *(const s8v*)&Bl[(nt * 16 + nl) * LPAD + q * 8];
            acc[0][nt] = MFMA_BF16(ah0, bh, acc[0][nt]);
            acc[0][nt] = MFMA_BF16(ah0, bl, acc[0][nt]);
            acc[0][nt] = MFMA_BF16(al0, bh, acc[0][nt]);
            acc[1][nt] = MFMA_BF16(ah1, bh, acc[1][nt]);
            acc[1][nt] = MFMA_BF16(ah1, bl, acc[1][nt]);
            acc[1][nt] = MFMA_BF16(al1, bh, acc[1][nt]);
        }
    }
    __syncthreads();   // LDS free for stats reuse

    float* redS = (float*)Ah;  // 4*128 floats
    float* redQ = (float*)Al;
#pragma unroll
    for (int nt = 0; nt < 8; ++nt) {
        int col = nt * 16 + nl;
        float bcol = bias[col];
        float sv = 0.f, qv = 0.f;
#pragma unroll
        for (int mt = 0; mt < 2; ++mt) {
#pragma unroll
            for (int r = 0; r < 4; ++r) {
                int grow = rbase + w * 32 + mt * 16 + q * 4 + r;
                if (grow < Nrows) {
                    float o = acc[mt][nt][r] + bcol;
                    C[(size_t)grow * HID + col] = o;
                    if (POST_STATS) { sv += o; qv += o * o; }
                }
            }
        }
        if (POST_STATS) {
            sv += __shfl_down(sv, 32, 64); sv += __shfl_down(sv, 16, 64);
            qv += __shfl_down(qv, 32, 64); qv += __shfl_down(qv, 16, 64);
            if ((tid & 63) < 16) { redS[w * 128 + col] = sv; redQ[w * 128 + col] = qv; }
        }
    }
    if (POST_STATS) {
        __syncthreads();
        if (tid < 128) {
            float S = redS[tid] + redS[128 + tid] + redS[256 + tid] + redS[384 + tid];
            float Q = redQ[tid] + redQ[128 + tid] + redQ[256 + tid] + redQ[384 + tid];
            atomicAdd(&postStats[tid], S);
            atomicAdd(&postStats[128 + tid], Q);
        }
    }
}

// ================= fused BN apply + ReLU + per-graph pooling (512 thr: 4 walkers) =================
__global__ void bn_apply_pool(const float* __restrict__ X, float* __restrict__ h,
                              const float* __restrict__ stats, const float* __restrict__ g,
                              const float* __restrict__ b, const int* __restrict__ starts,
                              float* __restrict__ z, int l, float invN)
{
    int gph = blockIdx.x;
    int tid = threadIdx.x;
    int j = tid & 127, q = tid >> 7;
    float mean = stats[j] * invN;
    float var = stats[128 + j] * invN - mean * mean;
    float rstd = rsqrtf(var + 1e-5f);
    float gg = g[j];
    float scale = rstd * gg;
    float shift = b[j] - mean * rstd * gg;
    int s = starts[gph], e = starts[gph + 1];
    float sum = 0.f, mx = 0.f;
    for (int n = s + q; n < e; n += 4) {
        float v = fmaxf(X[(long)n * HID + j] * scale + shift, 0.f);
        h[(long)n * HID + j] = v;
        sum += v; mx = fmaxf(mx, v);
    }
    __shared__ float ls[512], lm[512];
    ls[tid] = sum; lm[tid] = mx;
    __syncthreads();
    if (tid < 128) {
        sum = ls[tid] + ls[tid + 128] + ls[tid + 256] + ls[tid + 384];
        mx = fmaxf(fmaxf(lm[tid], lm[tid + 128]), fmaxf(lm[tid + 256], lm[tid + 384]));
        float cnt = (float)(e - s);
        z[(long)gph * 768 + l * 128 + tid] = sum / fmaxf(cnt, 1.f);
        z[(long)gph * 768 + 384 + l * 128 + tid] = mx;
    }
}

// ================= segment boundaries (batch sorted) =================
__global__ void starts_kernel(const int* __restrict__ batch, int* __restrict__ starts,
                              int Nn, int Gn)
{
    int g = blockIdx.x * blockDim.x + threadIdx.x;
    if (g > Gn) return;
    int lo = 0, hi = Nn;
    while (lo < hi) { int mid = (lo + hi) >> 1; if (batch[mid] < g) lo = mid + 1; else hi = mid; }
    starts[g] = lo;
}

// ================= head =================
__global__ void head_gemm1(const float* __restrict__ z, const float* __restrict__ W,
                           const float* __restrict__ bias, float* __restrict__ zr)
{
    __shared__ __align__(16) float zl[768];
    int g = blockIdx.x, j = threadIdx.x;
    for (int i = j; i < 768; i += 128) zl[i] = z[(long)g * 768 + i];
    __syncthreads();
    float acc = bias[j];
    for (int k = 0; k < 768; k += 4) {
        float4 a4 = *(const float4*)&zl[k];
        acc += a4.x * W[k * 128 + j] + a4.y * W[(k + 1) * 128 + j]
             + a4.z * W[(k + 2) * 128 + j] + a4.w * W[(k + 3) * 128 + j];
    }
    zr[(long)g * 128 + j] = acc;
}

__global__ void head_stats(const float* __restrict__ zr, float* __restrict__ ms, int Gn)
{
    int j = threadIdx.x;
    float sum = 0.f, sq = 0.f;
    for (int r = 0; r < Gn; ++r) { float v = zr[(long)r * 128 + j]; sum += v; sq += v * v; }
    float mean = sum / (float)Gn;
    float var = sq / (float)Gn - mean * mean;
    ms[j] = mean;
    ms[128 + j] = rsqrtf(var + 1e-5f);
}

__global__ void head_final(const float* __restrict__ zr, const float* __restrict__ ms,
                           const float* __restrict__ hg, const float* __restrict__ hb,
                           const float* __restrict__ W2, const float* __restrict__ b2,
                           float* __restrict__ out)
{
    int g = blockIdx.x, j = threadIdx.x;
    float v = zr[(long)g * 128 + j];
    v = (v - ms[j]) * ms[128 + j] * hg[j] + hb[j];
    v = fmaxf(v, 0.f);
    float p = v * W2[j];
#pragma unroll
    for (int off = 32; off > 0; off >>= 1) p += __shfl_down(p, off, 64);
    __shared__ float partial[2];
    if ((j & 63) == 0) partial[j >> 6] = p;
    __syncthreads();
    if (j == 0) out[g] = partial[0] + partial[1] + b2[0];
}

extern "C" void kernel_launch(void* const* d_in, const int* in_sizes, int n_in,
                              void* d_out, int out_size, void* d_ws, size_t ws_size,
                              hipStream_t stream)
{
    const float* x         = (const float*)d_in[0];
    const float* edge_attr = (const float*)d_in[1];
    const int*   src       = (const int*)d_in[2];
    const int*   dst       = (const int*)d_in[3];
    const int*   batch     = (const int*)d_in[4];
    const float* Wp        = (const float*)d_in[5];
    const float* bp        = (const float*)d_in[6];
    const float* conv_We   = (const float*)d_in[7];
    const float* conv_be   = (const float*)d_in[8];
    const float* conv_W1   = (const float*)d_in[9];
    const float* conv_b1   = (const float*)d_in[10];
    const float* conv_g1   = (const float*)d_in[11];
    const float* conv_bt1  = (const float*)d_in[12];
    const float* conv_W2   = (const float*)d_in[13];
    const float* conv_b2   = (const float*)d_in[14];
    const float* bn_g      = (const float*)d_in[15];
    const float* bn_b      = (const float*)d_in[16];
    const float* head_W1   = (const float*)d_in[17];
    const float* head_b1   = (const float*)d_in[18];
    const float* head_g    = (const float*)d_in[19];
    const float* head_bt   = (const float*)d_in[20];
    const float* head_W2   = (const float*)d_in[21];
    const float* head_b2   = (const float*)d_in[22];

    const int N = in_sizes[4];            // 50000
    const int E = in_sizes[2];            // 800000
    const int G = out_size;               // 256
    const int L = 3;

    // ---- workspace layout ----
    float* h        = (float*)d_ws;                  // N*128
    float* t        = h + (long)N * HID;             // N*128
    float* z        = t + (long)N * HID;             // G*768
    float* zr       = z + (long)G * 768;             // G*128
    float* statsAll = zr + (long)G * HID;            // 7*256
    int*   starts   = (int*)(statsAll + 7 * 256);    // G+1
    int*   row_start= starts + (G + 1);              // N+1
    int*   cursor   = row_start + (N + 1);           // N
    int*   deg      = cursor + N;                    // N
    int*   bsum     = deg + N;                       // 256
    int*   perm     = bsum + 256;                    // E
    int*   src_perm = perm + E;                      // E
    unsigned short* wt = (unsigned short*)(src_perm + E);  // 212992 ushorts (weights split-bf16)
    size_t base_end = (size_t)((char*)(wt + 212992) - (char*)d_ws);
    size_t ea_off = (base_end + 15) & ~(size_t)15;
    bool gath = (ea_off + (size_t)E * EDIM * sizeof(float)) <= ws_size;
    float* ea_perm = (float*)((char*)d_ws + ea_off);
    float* ms = statsAll + 6 * 256;

    const unsigned short* Wp_hi = wt;
    const unsigned short* Wp_lo = wt + 8192;

    (void)n_in;

    const float invN = 1.0f / (float)N;
    const int nb = (N + 255) / 256;
    const int gemmBlocks = (N + 127) / 128;

    // ---- CSR build + weight prep ----
    (void)hipMemsetAsync(deg, 0, (size_t)N * sizeof(int), stream);
    hist_kernel<<<(E + 255) / 256, 256, 0, stream>>>(dst, deg, E);
    block_sum_kernel<<<nb, 256, 0, stream>>>(deg, bsum, N);
    bsum_scan_kernel<<<1, 256, 0, stream>>>(bsum, nb, &row_start[N]);
    block_scan_kernel<<<nb, 256, 0, stream>>>(deg, bsum, row_start, cursor, N);
    scatter_kernel<<<(E + 255) / 256, 256, 0, stream>>>(src, dst, cursor, perm, src_perm, E);
    if (gath)
        gather_ea_kernel<<<(E * 4 + 255) / 256, 256, 0, stream>>>(edge_attr, perm, ea_perm, E);
    starts_kernel<<<1, 512, 0, stream>>>(batch, starts, N, G);
    prep_weights<<<(8192 + 6 * 16384 + 255) / 256, 256, 0, stream>>>(Wp, conv_W1, conv_W2, wt);
    (void)hipMemsetAsync(statsAll, 0, 7 * 256 * sizeof(float), stream);

    // h = x @ Wp + bp
    gemm_mfma<64, false, false><<<gemmBlocks, 256, 0, stream>>>(
        x, Wp_hi, Wp_lo, bp, nullptr, nullptr, nullptr, h, nullptr, N, invN);

    for (int l = 0; l < L; ++l) {
        float* sI = statsAll + l * 512;
        float* sO = sI + 256;
        const unsigned short* W1hi = wt + 16384 + (size_t)(2 * l) * 32768;
        const unsigned short* W1lo = W1hi + 16384;
        const unsigned short* W2hi = wt + 16384 + (size_t)(2 * l + 1) * 32768;
        const unsigned short* W2lo = W2hi + 16384;
        if (gath)
            aggregate_kernel<true><<<(N + 3) / 4, 256, 0, stream>>>(
                h, ea_perm, perm, src_perm, row_start,
                conv_We + (long)l * EDIM * HID, conv_be + l * HID, t, N);
        else
            aggregate_kernel<false><<<(N + 3) / 4, 256, 0, stream>>>(
                h, edge_attr, perm, src_perm, row_start,
                conv_We + (long)l * EDIM * HID, conv_be + l * HID, t, N);
        // t = t @ W1 + b1, fused inner-BN stats
        gemm_mfma<128, false, true><<<gemmBlocks, 256, 0, stream>>>(
            t, W1hi, W1lo, conv_b1 + l * HID,
            nullptr, nullptr, nullptr, t, sI, N, invN);
        // t = relu(BN_inner(t)) @ W2 + b2, fused outer-BN stats
        gemm_mfma<128, true, true><<<gemmBlocks, 256, 0, stream>>>(
            t, W2hi, W2lo, conv_b2 + l * HID,
            sI, conv_g1 + l * HID, conv_bt1 + l * HID, t, sO, N, invN);
        // h = relu(BN_outer(t)); pool into z slices in the same pass
        bn_apply_pool<<<G, 512, 0, stream>>>(
            t, h, sO, bn_g + l * HID, bn_b + l * HID, starts, z, l, invN);
    }

    head_gemm1<<<G, 128, 0, stream>>>(z, head_W1, head_b1, zr);
    head_stats<<<1, 128, 0, stream>>>(zr, ms, G);
    head_final<<<G, 128, 0, stream>>>(zr, ms, head_g, head_bt, head_W2, head_b2, (float*)d_out);
}

// Round 9
// 719.166 us; speedup vs baseline: 2.7328x; 1.1735x over previous
//
#include <hip/hip_runtime.h>
#include <hip/hip_bf16.h>

#define HID 128
#define EDIM 16

typedef float v4f __attribute__((ext_vector_type(4)));
typedef float v2f __attribute__((ext_vector_type(2)));
typedef short s8v __attribute__((ext_vector_type(8)));   // 8 bf16 (4 VGPRs) MFMA frag
typedef float f4v __attribute__((ext_vector_type(4)));   // MFMA acc

#define MFMA_BF16(a, b, c) __builtin_amdgcn_mfma_f32_16x16x32_bf16((a), (b), (c), 0, 0, 0)

__device__ __forceinline__ unsigned short bf16_rne(float v)
{
    unsigned u = __builtin_bit_cast(unsigned, v);
    return (unsigned short)((u + 0x7fffu + ((u >> 16) & 1u)) >> 16);
}

__device__ __forceinline__ void split_bf16(float v, unsigned short& h, unsigned short& l)
{
    unsigned u = __builtin_bit_cast(unsigned, v);
    unsigned hu = (u + 0x7fffu + ((u >> 16) & 1u)) >> 16;
    h = (unsigned short)hu;
    float hf = __builtin_bit_cast(float, hu << 16);
    l = bf16_rne(v - hf);
}

__device__ __forceinline__ v2f vmax0(v2f a)
{
    v2f r; r.x = fmaxf(a.x, 0.f); r.y = fmaxf(a.y, 0.f); return r;
}

// ================= CSR build =================
__global__ void hist_kernel(const int* __restrict__ dst, int* __restrict__ deg, int E)
{
    int e = blockIdx.x * 256 + threadIdx.x;
    if (e < E) atomicAdd(&deg[dst[e]], 1);
}

__global__ void block_sum_kernel(const int* __restrict__ deg, int* __restrict__ bsum, int Nn)
{
    int i = blockIdx.x * 256 + threadIdx.x;
    int v = (i < Nn) ? deg[i] : 0;
#pragma unroll
    for (int off = 32; off > 0; off >>= 1) v += __shfl_down(v, off, 64);
    __shared__ int ws[4];
    if ((threadIdx.x & 63) == 0) ws[threadIdx.x >> 6] = v;
    __syncthreads();
    if (threadIdx.x == 0) bsum[blockIdx.x] = ws[0] + ws[1] + ws[2] + ws[3];
}

__global__ void bsum_scan_kernel(int* bsum, int nb, int* total_out)
{
    __shared__ int sh[256];
    int tid = threadIdx.x;
    int v = (tid < nb) ? bsum[tid] : 0;
    sh[tid] = v;
    __syncthreads();
    for (int off = 1; off < 256; off <<= 1) {
        int tv = (tid >= off) ? sh[tid - off] : 0;
        __syncthreads();
        sh[tid] += tv;
        __syncthreads();
    }
    if (tid < nb) bsum[tid] = sh[tid] - v;
    if (tid == 255) *total_out = sh[255];
}

__global__ void block_scan_kernel(const int* __restrict__ deg, const int* __restrict__ bsum,
                                  int* __restrict__ row_start, int* __restrict__ cursor, int Nn)
{
    __shared__ int sh[256];
    int tid = threadIdx.x;
    int i = blockIdx.x * 256 + tid;
    int v = (i < Nn) ? deg[i] : 0;
    sh[tid] = v;
    __syncthreads();
    for (int off = 1; off < 256; off <<= 1) {
        int tv = (tid >= off) ? sh[tid - off] : 0;
        __syncthreads();
        sh[tid] += tv;
        __syncthreads();
    }
    if (i < Nn) {
        int excl = sh[tid] - v + bsum[blockIdx.x];
        row_start[i] = excl;
        cursor[i] = excl;
    }
}

// scatter + fused edge_attr permute-copy (GATH) — no separate gather pass
template<bool COPY_EA>
__global__ void scatter_kernel(const int* __restrict__ src, const int* __restrict__ dst,
                               int* cursor, int* __restrict__ perm,
                               int* __restrict__ src_perm,
                               const float* __restrict__ ea, float* __restrict__ ea_perm,
                               int E)
{
    int e = blockIdx.x * 256 + threadIdx.x;
    if (e >= E) return;
    int pos = atomicAdd(&cursor[dst[e]], 1);
    src_perm[pos] = src[e];
    if (COPY_EA) {
        const float4* s4 = (const float4*)(ea + (size_t)e * EDIM);
        float4* d4 = (float4*)(ea_perm + (size_t)pos * EDIM);
        d4[0] = s4[0]; d4[1] = s4[1]; d4[2] = s4[2]; d4[3] = s4[3];
    } else {
        perm[pos] = e;
    }
}

// ================= weight prep: fp32 [K,128] -> transposed split-bf16 [128,K] hi/lo =================
__global__ void prep_weights(const float* __restrict__ Wp, const float* __restrict__ W1,
                             const float* __restrict__ W2, unsigned short* __restrict__ out)
{
    int idx = blockIdx.x * 256 + threadIdx.x;
    if (idx < 8192) {
        int n = idx >> 6, k = idx & 63;
        unsigned short h, l;
        split_bf16(Wp[k * 128 + n], h, l);
        out[idx] = h;
        out[8192 + idx] = l;
    } else {
        int j = idx - 8192;
        if (j >= 6 * 16384) return;
        int m2 = j >> 14;
        int r = j & 16383;
        int n = r >> 7, k = r & 127;
        int l = m2 >> 1;
        const float* Wsrc = (m2 & 1) ? (W2 + l * 16384) : (W1 + l * 16384);
        unsigned short h, lo;
        split_bf16(Wsrc[k * 128 + n], h, lo);
        int base = 16384 + m2 * 32768;
        out[base + r] = h;
        out[base + 16384 + r] = lo;
    }
}

// ====== Node-centric aggregation: 1 wave/node, 2 ch/lane (packed f32), scalar-pipe ea ======
__device__ __forceinline__ void matvp(const v4f& a0, const v4f& a1,
                                      const v4f& a2, const v4f& a3,
                                      const v2f* __restrict__ w, v2f& m)
{
    m += w[0] * a0.x;  m += w[1] * a0.y;  m += w[2] * a0.z;  m += w[3] * a0.w;
    m += w[4] * a1.x;  m += w[5] * a1.y;  m += w[6] * a1.z;  m += w[7] * a1.w;
    m += w[8] * a2.x;  m += w[9] * a2.y;  m += w[10] * a2.z; m += w[11] * a2.w;
    m += w[12] * a3.x; m += w[13] * a3.y; m += w[14] * a3.z; m += w[15] * a3.w;
}

template<bool GATH>
__global__ __launch_bounds__(256, 6) void aggregate_kernel(
    const float* __restrict__ h, const float* __restrict__ eaG,
    const int* __restrict__ perm, const int* __restrict__ src_perm,
    const int* __restrict__ row_start,
    const float* __restrict__ We, const float* __restrict__ be,
    float* __restrict__ t, int Nn)
{
    int tid = threadIdx.x;
    int c = (tid & 63) * 2;
    v2f w[16];
#pragma unroll
    for (int k = 0; k < 16; ++k) w[k] = *(const v2f*)&We[k * HID + c];
    v2f bj = *(const v2f*)&be[c];
    int node = blockIdx.x * 4 + (tid >> 6);
    if (node >= Nn) return;
    const float* __restrict__ hc = h + c;
    v2f acc = *(const v2f*)(hc + ((unsigned)node << 7));
    int p0 = __builtin_amdgcn_readfirstlane(row_start[node]);
    int p1 = __builtin_amdgcn_readfirstlane(row_start[node + 1]);
    int p = p0;
    int s0 = 0, s1 = 0, s2 = 0, s3 = 0;
    if (p + 4 <= p1) { s0 = src_perm[p]; s1 = src_perm[p + 1]; s2 = src_perm[p + 2]; s3 = src_perm[p + 3]; }
    while (p + 4 <= p1) {
        int np = p + 4;
        int t0 = 0, t1 = 0, t2 = 0, t3 = 0;
        if (np + 4 <= p1) { t0 = src_perm[np]; t1 = src_perm[np + 1]; t2 = src_perm[np + 2]; t3 = src_perm[np + 3]; }
        v2f h0 = *(const v2f*)(hc + ((unsigned)s0 << 7));
        v2f h1 = *(const v2f*)(hc + ((unsigned)s1 << 7));
        v2f h2 = *(const v2f*)(hc + ((unsigned)s2 << 7));
        v2f h3 = *(const v2f*)(hc + ((unsigned)s3 << 7));
        int q0, q1, q2, q3;
        if (GATH) { q0 = p; q1 = p + 1; q2 = p + 2; q3 = p + 3; }
        else      { q0 = perm[p]; q1 = perm[p + 1]; q2 = perm[p + 2]; q3 = perm[p + 3]; }
        const v4f* e0 = (const v4f*)(eaG + (size_t)(unsigned)q0 * EDIM);
        const v4f* e1 = (const v4f*)(eaG + (size_t)(unsigned)q1 * EDIM);
        const v4f* e2 = (const v4f*)(eaG + (size_t)(unsigned)q2 * EDIM);
        const v4f* e3 = (const v4f*)(eaG + (size_t)(unsigned)q3 * EDIM);
        v4f a00 = e0[0], a01 = e0[1], a02 = e0[2], a03 = e0[3];
        v4f a10 = e1[0], a11 = e1[1], a12 = e1[2], a13 = e1[3];
        v4f a20 = e2[0], a21 = e2[1], a22 = e2[2], a23 = e2[3];
        v4f a30 = e3[0], a31 = e3[1], a32 = e3[2], a33 = e3[3];
        v2f m0 = bj + h0, m1 = bj + h1, m2 = bj + h2, m3 = bj + h3;
        matvp(a00, a01, a02, a03, w, m0);
        matvp(a10, a11, a12, a13, w, m1);
        matvp(a20, a21, a22, a23, w, m2);
        matvp(a30, a31, a32, a33, w, m3);
        acc += vmax0(m0) + vmax0(m1) + vmax0(m2) + vmax0(m3);
        p = np;
        s0 = t0; s1 = t1; s2 = t2; s3 = t3;
    }
    for (; p < p1; ++p) {
        int s = src_perm[p];
        int q = GATH ? p : perm[p];
        const v4f* e0 = (const v4f*)(eaG + (size_t)(unsigned)q * EDIM);
        v4f a0 = e0[0], a1 = e0[1], a2 = e0[2], a3 = e0[3];
        v2f hv = *(const v2f*)(hc + ((unsigned)s << 7));
        v2f m0 = bj + hv;
        matvp(a0, a1, a2, a3, w, m0);
        acc += vmax0(m0);
    }
    *(v2f*)(t + ((unsigned)node << 7) + c) = acc;
}

// ================= split-bf16 MFMA GEMM (unchanged from R8) =================
#define LPAD 40

template<int K, bool PRE_BN, bool POST_STATS>
__global__ __launch_bounds__(256) void gemm_mfma(
    const float* __restrict__ A, const unsigned short* __restrict__ Wh,
    const unsigned short* __restrict__ Wl, const float* __restrict__ bias,
    const float* __restrict__ preStats, const float* __restrict__ preG, const float* __restrict__ preB,
    float* __restrict__ C, float* __restrict__ postStats, int Nrows, float invN)
{
    __shared__ __align__(16) unsigned short Ah[128 * LPAD], Al[128 * LPAD];
    __shared__ __align__(16) unsigned short Bh[128 * LPAD], Bl[128 * LPAD];
    __shared__ float sc[PRE_BN ? K : 1], sb[PRE_BN ? K : 1];
    int tid = threadIdx.x;
    int rbase = blockIdx.x * 128;
    if (PRE_BN) {
        if (tid < K) {
            float mean = preStats[tid] * invN;
            float var = preStats[K + tid] * invN - mean * mean;
            float rstd = rsqrtf(var + 1e-5f);
            float g = preG[tid];
            sc[tid] = rstd * g;
            sb[tid] = preB[tid] - mean * rstd * g;
        }
        __syncthreads();
    }
    int w = tid >> 6, nl = tid & 15, q = (tid >> 4) & 3;
    f4v acc[2][8];
#pragma unroll
    for (int mt = 0; mt < 2; ++mt)
#pragma unroll
        for (int nt = 0; nt < 8; ++nt)
#pragma unroll
            for (int r = 0; r < 4; ++r) acc[mt][nt][r] = 0.f;

    for (int ks = 0; ks < K / 32; ++ks) {
        int k0 = ks * 32;
        if (ks) __syncthreads();
#pragma unroll
        for (int i = 0; i < 4; ++i) {
            int cidx = tid + i * 256;
            int m = cidx >> 3, k4 = (cidx & 7) * 4;
            int gr = rbase + m;
            float4 v = make_float4(0.f, 0.f, 0.f, 0.f);
            if (gr < Nrows) v = *(const float4*)&A[(size_t)gr * K + k0 + k4];
            if (PRE_BN) {
                v.x = fmaxf(v.x * sc[k0 + k4]     + sb[k0 + k4],     0.f);
                v.y = fmaxf(v.y * sc[k0 + k4 + 1] + sb[k0 + k4 + 1], 0.f);
                v.z = fmaxf(v.z * sc[k0 + k4 + 2] + sb[k0 + k4 + 2], 0.f);
                v.w = fmaxf(v.w * sc[k0 + k4 + 3] + sb[k0 + k4 + 3], 0.f);
            }
            unsigned short h0, l0, h1, l1, h2, l2, h3, l3;
            split_bf16(v.x, h0, l0); split_bf16(v.y, h1, l1);
            split_bf16(v.z, h2, l2); split_bf16(v.w, h3, l3);
            uint2 hp, lp;
            hp.x = (unsigned)h0 | ((unsigned)h1 << 16); hp.y = (unsigned)h2 | ((unsigned)h3 << 16);
            lp.x = (unsigned)l0 | ((unsigned)l1 << 16); lp.y = (unsigned)l2 | ((unsigned)l3 << 16);
            *(uint2*)&Ah[m * LPAD + k4] = hp;
            *(uint2*)&Al[m * LPAD + k4] = lp;
        }
#pragma unroll
        for (int i = 0; i < 2; ++i) {
            int g = tid + i * 256;
            int n = g >> 2, kq = (g & 3) * 8;
            uint4 hv = *(const uint4*)&Wh[(size_t)n * K + k0 + kq];
            uint4 lv = *(const uint4*)&Wl[(size_t)n * K + k0 + kq];
            *(uint4*)&Bh[n * LPAD + kq] = hv;
            *(uint4*)&Bl[n * LPAD + kq] = lv;
        }
        __syncthreads();
        s8v ah0 = *(const s8v*)&Ah[(w * 32 + nl) * LPAD + q * 8];
        s8v ah1 = *(const s8v*)&Ah[(w * 32 + 16 + nl) * LPAD + q * 8];
        s8v al0 = *(const s8v*)&Al[(w * 32 + nl) * LPAD + q * 8];
        s8v al1 = *(const s8v*)&Al[(w * 32 + 16 + nl) * LPAD + q * 8];
#pragma unroll
        for (int nt = 0; nt < 8; ++nt) {
            s8v bh = *(const s8v*)&Bh[(nt * 16 + nl) * LPAD + q * 8];
            s8v bl = *(const s8v*)&Bl[(nt * 16 + nl) * LPAD + q * 8];
            acc[0][nt] = MFMA_BF16(ah0, bh, acc[0][nt]);
            acc[0][nt] = MFMA_BF16(ah0, bl, acc[0][nt]);
            acc[0][nt] = MFMA_BF16(al0, bh, acc[0][nt]);
            acc[1][nt] = MFMA_BF16(ah1, bh, acc[1][nt]);
            acc[1][nt] = MFMA_BF16(ah1, bl, acc[1][nt]);
            acc[1][nt] = MFMA_BF16(al1, bh, acc[1][nt]);
        }
    }
    __syncthreads();

    float* redS = (float*)Ah;
    float* redQ = (float*)Al;
#pragma unroll
    for (int nt = 0; nt < 8; ++nt) {
        int col = nt * 16 + nl;
        float bcol = bias[col];
        float sv = 0.f, qv = 0.f;
#pragma unroll
        for (int mt = 0; mt < 2; ++mt) {
#pragma unroll
            for (int r = 0; r < 4; ++r) {
                int grow = rbase + w * 32 + mt * 16 + q * 4 + r;
                if (grow < Nrows) {
                    float o = acc[mt][nt][r] + bcol;
                    C[(size_t)grow * HID + col] = o;
                    if (POST_STATS) { sv += o; qv += o * o; }
                }
            }
        }
        if (POST_STATS) {
            sv += __shfl_down(sv, 32, 64); sv += __shfl_down(sv, 16, 64);
            qv += __shfl_down(qv, 32, 64); qv += __shfl_down(qv, 16, 64);
            if ((tid & 63) < 16) { redS[w * 128 + col] = sv; redQ[w * 128 + col] = qv; }
        }
    }
    if (POST_STATS) {
        __syncthreads();
        if (tid < 128) {
            float S = redS[tid] + redS[128 + tid] + redS[256 + tid] + redS[384 + tid];
            float Q = redQ[tid] + redQ[128 + tid] + redQ[256 + tid] + redQ[384 + tid];
            atomicAdd(&postStats[tid], S);
            atomicAdd(&postStats[128 + tid], Q);
        }
    }
}

// ======== fused BN apply + ReLU + per-graph pooling: 512 thr = 16 row-walkers x 32 lanes(float4) ========
__global__ void bn_apply_pool(const float* __restrict__ X, float* __restrict__ h,
                              const float* __restrict__ stats, const float* __restrict__ g,
                              const float* __restrict__ b, const int* __restrict__ starts,
                              float* __restrict__ z, int l, float invN)
{
    int gph = blockIdx.x;
    int tid = threadIdx.x;
    int ch4 = (tid & 31) * 4, wk = tid >> 5;   // 16 walkers
    float sc[4], sh[4];
#pragma unroll
    for (int u = 0; u < 4; ++u) {
        int j = ch4 + u;
        float mean = stats[j] * invN;
        float var = stats[128 + j] * invN - mean * mean;
        float rstd = rsqrtf(var + 1e-5f);
        float gg = g[j];
        sc[u] = rstd * gg;
        sh[u] = b[j] - mean * rstd * gg;
    }
    int s = starts[gph], e = starts[gph + 1];
    float4 sum = make_float4(0.f, 0.f, 0.f, 0.f);
    float4 mx = make_float4(0.f, 0.f, 0.f, 0.f);
    for (int n = s + wk; n < e; n += 16) {
        float4 v = *(const float4*)&X[(size_t)n * HID + ch4];
        v.x = fmaxf(v.x * sc[0] + sh[0], 0.f);
        v.y = fmaxf(v.y * sc[1] + sh[1], 0.f);
        v.z = fmaxf(v.z * sc[2] + sh[2], 0.f);
        v.w = fmaxf(v.w * sc[3] + sh[3], 0.f);
        *(float4*)&h[(size_t)n * HID + ch4] = v;
        sum.x += v.x; sum.y += v.y; sum.z += v.z; sum.w += v.w;
        mx.x = fmaxf(mx.x, v.x); mx.y = fmaxf(mx.y, v.y);
        mx.z = fmaxf(mx.z, v.z); mx.w = fmaxf(mx.w, v.w);
    }
    __shared__ float ls[16 * 128], lm[16 * 128];
    *(float4*)&ls[wk * 128 + ch4] = sum;
    *(float4*)&lm[wk * 128 + ch4] = mx;
    __syncthreads();
    if (tid < 128) {
        float S = 0.f, M = 0.f;
#pragma unroll
        for (int k = 0; k < 16; ++k) {
            S += ls[k * 128 + tid];
            M = fmaxf(M, lm[k * 128 + tid]);
        }
        float cnt = (float)(e - s);
        z[(size_t)gph * 768 + l * 128 + tid] = S / fmaxf(cnt, 1.f);
        z[(size_t)gph * 768 + 384 + l * 128 + tid] = M;
    }
}

// ================= segment boundaries (batch sorted) =================
__global__ void starts_kernel(const int* __restrict__ batch, int* __restrict__ starts,
                              int Nn, int Gn)
{
    int g = blockIdx.x * blockDim.x + threadIdx.x;
    if (g > Gn) return;
    int lo = 0, hi = Nn;
    while (lo < hi) { int mid = (lo + hi) >> 1; if (batch[mid] < g) lo = mid + 1; else hi = mid; }
    starts[g] = lo;
}

// ================= head: GEMM1 with fused stats atomics =================
__global__ void head_gemm1(const float* __restrict__ z, const float* __restrict__ W,
                           const float* __restrict__ bias, float* __restrict__ zr,
                           float* __restrict__ msums)
{
    __shared__ __align__(16) float zl[768];
    int g = blockIdx.x, j = threadIdx.x;
    for (int i = j; i < 768; i += 128) zl[i] = z[(size_t)g * 768 + i];
    __syncthreads();
    float acc = bias[j];
    for (int k = 0; k < 768; k += 4) {
        float4 a4 = *(const float4*)&zl[k];
        acc += a4.x * W[k * 128 + j] + a4.y * W[(k + 1) * 128 + j]
             + a4.z * W[(k + 2) * 128 + j] + a4.w * W[(k + 3) * 128 + j];
    }
    zr[(size_t)g * 128 + j] = acc;
    atomicAdd(&msums[j], acc);
    atomicAdd(&msums[128 + j], acc * acc);
}

__global__ void head_final(const float* __restrict__ zr, const float* __restrict__ msums,
                           const float* __restrict__ hg, const float* __restrict__ hb,
                           const float* __restrict__ W2, const float* __restrict__ b2,
                           float* __restrict__ out, float invG)
{
    int g = blockIdx.x, j = threadIdx.x;
    float mean = msums[j] * invG;
    float var = msums[128 + j] * invG - mean * mean;
    float rstd = rsqrtf(var + 1e-5f);
    float v = zr[(size_t)g * 128 + j];
    v = (v - mean) * rstd * hg[j] + hb[j];
    v = fmaxf(v, 0.f);
    float p = v * W2[j];
#pragma unroll
    for (int off = 32; off > 0; off >>= 1) p += __shfl_down(p, off, 64);
    __shared__ float partial[2];
    if ((j & 63) == 0) partial[j >> 6] = p;
    __syncthreads();
    if (j == 0) out[g] = partial[0] + partial[1] + b2[0];
}

extern "C" void kernel_launch(void* const* d_in, const int* in_sizes, int n_in,
                              void* d_out, int out_size, void* d_ws, size_t ws_size,
                              hipStream_t stream)
{
    const float* x         = (const float*)d_in[0];
    const float* edge_attr = (const float*)d_in[1];
    const int*   src       = (const int*)d_in[2];
    const int*   dst       = (const int*)d_in[3];
    const int*   batch     = (const int*)d_in[4];
    const float* Wp        = (const float*)d_in[5];
    const float* bp        = (const float*)d_in[6];
    const float* conv_We   = (const float*)d_in[7];
    const float* conv_be   = (const float*)d_in[8];
    const float* conv_W1   = (const float*)d_in[9];
    const float* conv_b1   = (const float*)d_in[10];
    const float* conv_g1   = (const float*)d_in[11];
    const float* conv_bt1  = (const float*)d_in[12];
    const float* conv_W2   = (const float*)d_in[13];
    const float* conv_b2   = (const float*)d_in[14];
    const float* bn_g      = (const float*)d_in[15];
    const float* bn_b      = (const float*)d_in[16];
    const float* head_W1   = (const float*)d_in[17];
    const float* head_b1   = (const float*)d_in[18];
    const float* head_g    = (const float*)d_in[19];
    const float* head_bt   = (const float*)d_in[20];
    const float* head_W2   = (const float*)d_in[21];
    const float* head_b2   = (const float*)d_in[22];

    const int N = in_sizes[4];            // 50000
    const int E = in_sizes[2];            // 800000
    const int G = out_size;               // 256
    const int L = 3;

    // ---- workspace layout (statsAll and deg contiguous for single memset) ----
    float* h        = (float*)d_ws;                  // N*128
    float* t        = h + (size_t)N * HID;           // N*128
    float* z        = t + (size_t)N * HID;           // G*768
    float* zr       = z + (size_t)G * 768;           // G*128
    float* statsAll = zr + (size_t)G * HID;          // 7*256 (3x{inner,outer} + head msums)
    int*   deg      = (int*)(statsAll + 7 * 256);    // N
    int*   starts   = deg + N;                       // G+1
    int*   row_start= starts + (G + 1);              // N+1
    int*   cursor   = row_start + (N + 1);           // N
    int*   bsum     = cursor + N;                    // 256
    int*   src_perm = bsum + 256;                    // E
    int*   perm     = src_perm + E;                  // E (fallback only)
    unsigned short* wt = (unsigned short*)(perm + E);  // 212992 ushorts
    size_t base_end = (size_t)((char*)(wt + 212992) - (char*)d_ws);
    size_t ea_off = (base_end + 15) & ~(size_t)15;
    bool gath = (ea_off + (size_t)E * EDIM * sizeof(float)) <= ws_size;
    float* ea_perm = (float*)((char*)d_ws + ea_off);
    float* msums = statsAll + 6 * 256;

    (void)n_in;

    const float invN = 1.0f / (float)N;
    const float invG = 1.0f / (float)G;
    const int nb = (N + 255) / 256;
    const int gemmBlocks = (N + 127) / 128;

    // ---- CSR build + weight prep ----
    (void)hipMemsetAsync(statsAll, 0, 7 * 256 * sizeof(float) + (size_t)N * sizeof(int), stream);
    hist_kernel<<<(E + 255) / 256, 256, 0, stream>>>(dst, deg, E);
    block_sum_kernel<<<nb, 256, 0, stream>>>(deg, bsum, N);
    bsum_scan_kernel<<<1, 256, 0, stream>>>(bsum, nb, &row_start[N]);
    block_scan_kernel<<<nb, 256, 0, stream>>>(deg, bsum, row_start, cursor, N);
    if (gath)
        scatter_kernel<true><<<(E + 255) / 256, 256, 0, stream>>>(
            src, dst, cursor, perm, src_perm, edge_attr, ea_perm, E);
    else
        scatter_kernel<false><<<(E + 255) / 256, 256, 0, stream>>>(
            src, dst, cursor, perm, src_perm, edge_attr, ea_perm, E);
    starts_kernel<<<1, 512, 0, stream>>>(batch, starts, N, G);
    prep_weights<<<(8192 + 6 * 16384 + 255) / 256, 256, 0, stream>>>(Wp, conv_W1, conv_W2, wt);

    const unsigned short* Wp_hi = wt;
    const unsigned short* Wp_lo = wt + 8192;

    // h = x @ Wp + bp
    gemm_mfma<64, false, false><<<gemmBlocks, 256, 0, stream>>>(
        x, Wp_hi, Wp_lo, bp, nullptr, nullptr, nullptr, h, nullptr, N, invN);

    for (int l = 0; l < L; ++l) {
        float* sI = statsAll + l * 512;
        float* sO = sI + 256;
        const unsigned short* W1hi = wt + 16384 + (size_t)(2 * l) * 32768;
        const unsigned short* W1lo = W1hi + 16384;
        const unsigned short* W2hi = wt + 16384 + (size_t)(2 * l + 1) * 32768;
        const unsigned short* W2lo = W2hi + 16384;
        if (gath)
            aggregate_kernel<true><<<(N + 3) / 4, 256, 0, stream>>>(
                h, ea_perm, perm, src_perm, row_start,
                conv_We + (size_t)l * EDIM * HID, conv_be + l * HID, t, N);
        else
            aggregate_kernel<false><<<(N + 3) / 4, 256, 0, stream>>>(
                h, edge_attr, perm, src_perm, row_start,
                conv_We + (size_t)l * EDIM * HID, conv_be + l * HID, t, N);
        gemm_mfma<128, false, true><<<gemmBlocks, 256, 0, stream>>>(
            t, W1hi, W1lo, conv_b1 + l * HID,
            nullptr, nullptr, nullptr, t, sI, N, invN);
        gemm_mfma<128, true, true><<<gemmBlocks, 256, 0, stream>>>(
            t, W2hi, W2lo, conv_b2 + l * HID,
            sI, conv_g1 + l * HID, conv_bt1 + l * HID, t, sO, N, invN);
        bn_apply_pool<<<G, 512, 0, stream>>>(
            t, h, sO, bn_g + l * HID, bn_b + l * HID, starts, z, l, invN);
    }

    head_gemm1<<<G, 128, 0, stream>>>(z, head_W1, head_b1, zr, msums);
    head_final<<<G, 128, 0, stream>>>(zr, msums, head_g, head_bt, head_W2, head_b2,
                                      (float*)d_out, invG);
}